// Round 1
// baseline (2650.699 us; speedup 1.0000x reference)
//
#include <hip/hip_runtime.h>
#include <cmath>

// ---------------------------------------------------------------------------
// BertLayer + top-2 MoE, MI355X. Round 1: correct fp32 baseline.
// B=8 S=512 H=768 NH=12 DH=64 I=3072 E=8 TOPK=2, T=B*S=4096 tokens.
// Sparse expert dispatch (only top-2 experts per token -> 116 GFLOP MoE
// instead of 464 dense). All GEMMs: 64x64 tile, 256 thr, 4x4/thread, LDS.
// ---------------------------------------------------------------------------

constexpr int cB = 8, cS = 512, cH = 768, cNH = 12, cDH = 64, cI = 3072, cE = 8;
constexpr int cT = cB * cS;                       // 4096 tokens
constexpr size_t TH = (size_t)cT * cH;            // 3,145,728 floats

// workspace layout (float units). q..attn live inside the act region but their
// lifetime ends (copy-to-out) before act is first written by expert_up.
constexpr size_t ACT_SZ     = (size_t)2 * cT * cI;   // 25,165,824 (8192 rows x I)
constexpr size_t OFF_Q      = 0;
constexpr size_t OFF_K      = TH;
constexpr size_t OFF_V      = 2 * TH;
constexpr size_t OFF_CTX    = 3 * TH;
constexpr size_t OFF_TMP    = 4 * TH;
constexpr size_t OFF_ATTN   = 5 * TH;
constexpr size_t OFF_ACT    = 0;
constexpr size_t OFF_XL     = ACT_SZ;
constexpr size_t OFF_WGT    = OFF_XL + TH;           // 2*T gate weights
constexpr size_t OFF_COUNTS = OFF_WGT + 2 * cT;      // int[16]
constexpr size_t OFF_LISTS  = OFF_COUNTS + 16;       // int[E*T]

__global__ void init_counts_kernel(int* __restrict__ counts) {
    if (threadIdx.x < cE) counts[threadIdx.x] = 0;
}

// C[M,N] = A[M,K] @ B[K,N] + bias[N].  M%64==0, N%64==0, K%16==0.
__global__ __launch_bounds__(256) void gemm_bias_kernel(
    const float* __restrict__ A, const float* __restrict__ B,
    const float* __restrict__ bias, float* __restrict__ C,
    int M, int N, int K) {
    __shared__ float As[16][65];   // [k][m], +1 pad
    __shared__ float Bs[16][64];   // [k][n]
    const int tid = threadIdx.x;
    const int m0 = blockIdx.y * 64, n0 = blockIdx.x * 64;
    const int tx = tid & 15, ty = tid >> 4;
    const int ar = tid >> 2, ac = (tid & 3) * 4;
    const int br = tid >> 4, bc = (tid & 15) * 4;
    float acc[4][4] = {};
    for (int k0 = 0; k0 < K; k0 += 16) {
        float4 av = *(const float4*)(A + (size_t)(m0 + ar) * K + k0 + ac);
        As[ac + 0][ar] = av.x; As[ac + 1][ar] = av.y;
        As[ac + 2][ar] = av.z; As[ac + 3][ar] = av.w;
        *(float4*)&Bs[br][bc] = *(const float4*)(B + (size_t)(k0 + br) * N + n0 + bc);
        __syncthreads();
#pragma unroll
        for (int kk = 0; kk < 16; ++kk) {
            float a[4], bv[4];
#pragma unroll
            for (int i = 0; i < 4; ++i) a[i] = As[kk][ty * 4 + i];
            *(float4*)bv = *(const float4*)&Bs[kk][tx * 4];
#pragma unroll
            for (int i = 0; i < 4; ++i)
#pragma unroll
                for (int j = 0; j < 4; ++j) acc[i][j] += a[i] * bv[j];
        }
        __syncthreads();
    }
#pragma unroll
    for (int i = 0; i < 4; ++i) {
        float4 o;
        o.x = acc[i][0] + bias[n0 + tx * 4 + 0];
        o.y = acc[i][1] + bias[n0 + tx * 4 + 1];
        o.z = acc[i][2] + bias[n0 + tx * 4 + 2];
        o.w = acc[i][3] + bias[n0 + tx * 4 + 3];
        *(float4*)(C + (size_t)(m0 + ty * 4 + i) * N + n0 + tx * 4) = o;
    }
}

// Fused attention: one block per (q-tile of 16 rows, head, batch).
__global__ __launch_bounds__(256) void attn_kernel(
    const float* __restrict__ q, const float* __restrict__ k,
    const float* __restrict__ v, float* __restrict__ ctx) {
    __shared__ float sQ[16][68];
    __shared__ float sKV[64][68];
    __shared__ float sP[16][516];
    const int qt = blockIdx.x, h = blockIdx.y, b = blockIdx.z;
    const int tid = threadIdx.x;
    {
        int r = tid >> 4, d = (tid & 15) * 4;
        *(float4*)&sQ[r][d] =
            *(const float4*)(q + (size_t)(b * cS + qt * 16 + r) * cH + h * cDH + d);
    }
    __syncthreads();
    const int r = tid & 15, cb = tid >> 4;
    for (int ct = 0; ct < 8; ++ct) {
#pragma unroll
        for (int i = 0; i < 4; ++i) {
            int c = (tid >> 4) + i * 16, d = (tid & 15) * 4;
            *(float4*)&sKV[c][d] =
                *(const float4*)(k + (size_t)(b * cS + ct * 64 + c) * cH + h * cDH + d);
        }
        __syncthreads();
        float acc[4] = {0.f, 0.f, 0.f, 0.f};
#pragma unroll
        for (int d = 0; d < 64; ++d) {
            float qv = sQ[r][d];
            acc[0] += qv * sKV[cb][d];
            acc[1] += qv * sKV[cb + 16][d];
            acc[2] += qv * sKV[cb + 32][d];
            acc[3] += qv * sKV[cb + 48][d];
        }
#pragma unroll
        for (int j = 0; j < 4; ++j) sP[r][ct * 64 + cb + 16 * j] = acc[j] * 0.125f;
        __syncthreads();
    }
    {
        const int wave = tid >> 6, lane = tid & 63;
        for (int rr = 0; rr < 4; ++rr) {
            int row = wave * 4 + rr;
            float vals[8], m = -1e30f;
#pragma unroll
            for (int i = 0; i < 8; ++i) {
                vals[i] = sP[row][lane + 64 * i];
                m = fmaxf(m, vals[i]);
            }
#pragma unroll
            for (int o = 32; o; o >>= 1) m = fmaxf(m, __shfl_xor(m, o));
            float s = 0.f;
#pragma unroll
            for (int i = 0; i < 8; ++i) { vals[i] = __expf(vals[i] - m); s += vals[i]; }
#pragma unroll
            for (int o = 32; o; o >>= 1) s += __shfl_xor(s, o);
            float inv = 1.0f / s;
#pragma unroll
            for (int i = 0; i < 8; ++i) sP[row][lane + 64 * i] = vals[i] * inv;
        }
    }
    __syncthreads();
    float o[4] = {0.f, 0.f, 0.f, 0.f};
    for (int vt = 0; vt < 8; ++vt) {
#pragma unroll
        for (int i = 0; i < 4; ++i) {
            int c = (tid >> 4) + i * 16, d = (tid & 15) * 4;
            *(float4*)&sKV[c][d] =
                *(const float4*)(v + (size_t)(b * cS + vt * 64 + c) * cH + h * cDH + d);
        }
        __syncthreads();
#pragma unroll
        for (int kk = 0; kk < 64; ++kk) {
            float p = sP[r][vt * 64 + kk];
            o[0] += p * sKV[kk][cb];
            o[1] += p * sKV[kk][cb + 16];
            o[2] += p * sKV[kk][cb + 32];
            o[3] += p * sKV[kk][cb + 48];
        }
        __syncthreads();
    }
#pragma unroll
    for (int j = 0; j < 4; ++j)
        ctx[(size_t)(b * cS + qt * 16 + r) * cH + h * cDH + cb + 16 * j] = o[j];
}

__device__ __forceinline__ float block_reduce_sum(float v, float* red) {
#pragma unroll
    for (int o = 32; o; o >>= 1) v += __shfl_xor(v, o);
    __syncthreads();
    if ((threadIdx.x & 63) == 0) red[threadIdx.x >> 6] = v;
    __syncthreads();
    return red[0] + red[1] + red[2] + red[3];
}

// attn_out = LN1(dense + resid); xl = LN2(attn_out). One block per token.
__global__ __launch_bounds__(256) void ln_fused_kernel(
    const float* __restrict__ dense, const float* __restrict__ resid,
    const float* __restrict__ g1, const float* __restrict__ b1,
    const float* __restrict__ g2, const float* __restrict__ b2,
    float* __restrict__ attn_out, float* __restrict__ xl) {
    __shared__ float red[4];
    const int t = blockIdx.x, tid = threadIdx.x;
    const size_t base = (size_t)t * cH;
    float v[3], s = 0.f;
#pragma unroll
    for (int i = 0; i < 3; ++i) {
        v[i] = dense[base + tid + 256 * i] + resid[base + tid + 256 * i];
        s += v[i];
    }
    const float mean = block_reduce_sum(s, red) * (1.0f / cH);
    float vs = 0.f;
#pragma unroll
    for (int i = 0; i < 3; ++i) { float d = v[i] - mean; vs += d * d; }
    const float rstd = rsqrtf(block_reduce_sum(vs, red) * (1.0f / cH) + 1e-12f);
    float a[3], s2 = 0.f;
#pragma unroll
    for (int i = 0; i < 3; ++i) {
        a[i] = (v[i] - mean) * rstd * g1[tid + 256 * i] + b1[tid + 256 * i];
        attn_out[base + tid + 256 * i] = a[i];
        s2 += a[i];
    }
    const float mean2 = block_reduce_sum(s2, red) * (1.0f / cH);
    float vs2 = 0.f;
#pragma unroll
    for (int i = 0; i < 3; ++i) { float d = a[i] - mean2; vs2 += d * d; }
    const float rstd2 = rsqrtf(block_reduce_sum(vs2, red) * (1.0f / cH) + 1e-12f);
#pragma unroll
    for (int i = 0; i < 3; ++i)
        xl[base + tid + 256 * i] =
            (a[i] - mean2) * rstd2 * g2[tid + 256 * i] + b2[tid + 256 * i];
}

// Router: one wave per token.
__global__ __launch_bounds__(256) void router_kernel(
    const float* __restrict__ xl, const float* __restrict__ Wr,
    const float* __restrict__ br, float* __restrict__ out_logits,
    float* __restrict__ wgt, int* __restrict__ counts, int* __restrict__ lists) {
    const int lane = threadIdx.x & 63;
    const int t = blockIdx.x * 4 + (threadIdx.x >> 6);
    const float* xr = xl + (size_t)t * cH;
    float acc[cE] = {};
#pragma unroll
    for (int i = 0; i < cH / 64; ++i) {
        float xv = xr[lane + 64 * i];
        const float* wr = Wr + (size_t)(lane + 64 * i) * cE;
#pragma unroll
        for (int e = 0; e < cE; ++e) acc[e] += xv * wr[e];
    }
#pragma unroll
    for (int e = 0; e < cE; ++e)
#pragma unroll
        for (int o = 32; o; o >>= 1) acc[e] += __shfl_xor(acc[e], o);
    if (lane == 0) {
        float logits[cE];
#pragma unroll
        for (int e = 0; e < cE; ++e) {
            logits[e] = acc[e] + br[e];
            out_logits[(size_t)t * cE + e] = logits[e];
        }
        int i0 = 0;
        for (int e = 1; e < cE; ++e) if (logits[e] > logits[i0]) i0 = e;
        int i1 = (i0 == 0) ? 1 : 0;
        for (int e = 0; e < cE; ++e)
            if (e != i0 && logits[e] > logits[i1]) i1 = e;
        float e1 = __expf(logits[i1] - logits[i0]);
        float w0 = 1.0f / (1.0f + e1);
        float w1 = e1 * w0;
        wgt[t * 2 + 0] = w0;
        wgt[t * 2 + 1] = w1;
        int p0 = atomicAdd(&counts[i0], 1);
        lists[i0 * cT + p0] = t * 2 + 0;
        int p1 = atomicAdd(&counts[i1], 1);
        lists[i1 * cT + p1] = t * 2 + 1;
    }
}

__global__ __launch_bounds__(256) void copy_kernel(
    const float* __restrict__ src, float* __restrict__ dst) {
    size_t i = ((size_t)blockIdx.x * 256 + threadIdx.x) * 4;
    *(float4*)(dst + i) = *(const float4*)(src + i);
}

// act[a,:] = gelu(xl @ W_up[e] + b_up) * (xl @ W_new[e] + b_new), gathered rows.
__global__ __launch_bounds__(256) void expert_up_kernel(
    const float* __restrict__ xl,
    const float* __restrict__ W_up, const float* __restrict__ b_up,
    const float* __restrict__ W_new, const float* __restrict__ b_new,
    const int* __restrict__ counts, const int* __restrict__ lists,
    float* __restrict__ act) {
    const int e = blockIdx.z;
    const int cnt = counts[e];
    const int m0 = blockIdx.y * 64;
    if (m0 >= cnt) return;
    const int n0 = blockIdx.x * 64;
    __shared__ float As[16][65];
    __shared__ float B1s[16][64];
    __shared__ float B2s[16][64];
    __shared__ int rowa[64];
    const int tid = threadIdx.x;
    if (tid < 64) {
        int idx = m0 + tid;
        rowa[tid] = (idx < cnt) ? lists[e * cT + idx] : -1;
    }
    __syncthreads();
    const float* B1 = W_up + (size_t)e * cH * cI;
    const float* B2 = W_new + (size_t)e * cH * cI;
    const int tx = tid & 15, ty = tid >> 4;
    const int ar = tid >> 2, ac = (tid & 3) * 4;
    const int brr = tid >> 4, bcc = (tid & 15) * 4;
    float acc1[4][4] = {}, acc2[4][4] = {};
    const int a_row = rowa[ar];
    const float* arow_ptr = (a_row >= 0) ? xl + (size_t)(a_row >> 1) * cH : nullptr;
    for (int k0 = 0; k0 < cH; k0 += 16) {
        float4 av = make_float4(0.f, 0.f, 0.f, 0.f);
        if (arow_ptr) av = *(const float4*)(arow_ptr + k0 + ac);
        As[ac + 0][ar] = av.x; As[ac + 1][ar] = av.y;
        As[ac + 2][ar] = av.z; As[ac + 3][ar] = av.w;
        *(float4*)&B1s[brr][bcc] = *(const float4*)(B1 + (size_t)(k0 + brr) * cI + n0 + bcc);
        *(float4*)&B2s[brr][bcc] = *(const float4*)(B2 + (size_t)(k0 + brr) * cI + n0 + bcc);
        __syncthreads();
#pragma unroll
        for (int kk = 0; kk < 16; ++kk) {
            float a[4], bv1[4], bv2[4];
#pragma unroll
            for (int i = 0; i < 4; ++i) a[i] = As[kk][ty * 4 + i];
            *(float4*)bv1 = *(const float4*)&B1s[kk][tx * 4];
            *(float4*)bv2 = *(const float4*)&B2s[kk][tx * 4];
#pragma unroll
            for (int i = 0; i < 4; ++i)
#pragma unroll
                for (int j = 0; j < 4; ++j) {
                    acc1[i][j] += a[i] * bv1[j];
                    acc2[i][j] += a[i] * bv2[j];
                }
        }
        __syncthreads();
    }
#pragma unroll
    for (int i = 0; i < 4; ++i) {
        int rr = ty * 4 + i;
        int a = rowa[rr];
        if (a < 0) continue;
        float* arow = act + (size_t)a * cI + n0;
#pragma unroll
        for (int j = 0; j < 4; ++j) {
            int n = tx * 4 + j;
            float up = acc1[i][j] + b_up[e * cI + n0 + n];
            float nw = acc2[i][j] + b_new[e * cI + n0 + n];
            float g = 0.5f * up * (1.0f + erff(up * 0.70710678118654752f));
            arow[n] = g * nw;
        }
    }
}

// out[token,:] += w[a] * (act[a,:] @ W_down[e] + b_down[e])
__global__ __launch_bounds__(256) void expert_down_kernel(
    const float* __restrict__ act,
    const float* __restrict__ W_down, const float* __restrict__ b_down,
    const int* __restrict__ counts, const int* __restrict__ lists,
    const float* __restrict__ wgt, float* __restrict__ out) {
    const int e = blockIdx.z;
    const int cnt = counts[e];
    const int m0 = blockIdx.y * 64;
    if (m0 >= cnt) return;
    const int n0 = blockIdx.x * 64;
    __shared__ float As[16][65];
    __shared__ float Bs[16][64];
    __shared__ int rowa[64];
    const int tid = threadIdx.x;
    if (tid < 64) {
        int idx = m0 + tid;
        rowa[tid] = (idx < cnt) ? lists[e * cT + idx] : -1;
    }
    __syncthreads();
    const float* Bm = W_down + (size_t)e * cI * cH;
    const int tx = tid & 15, ty = tid >> 4;
    const int ar = tid >> 2, ac = (tid & 3) * 4;
    const int brr = tid >> 4, bcc = (tid & 15) * 4;
    float acc[4][4] = {};
    const int a_row = rowa[ar];
    const float* arow_ptr = (a_row >= 0) ? act + (size_t)a_row * cI : nullptr;
    for (int k0 = 0; k0 < cI; k0 += 16) {
        float4 av = make_float4(0.f, 0.f, 0.f, 0.f);
        if (arow_ptr) av = *(const float4*)(arow_ptr + k0 + ac);
        As[ac + 0][ar] = av.x; As[ac + 1][ar] = av.y;
        As[ac + 2][ar] = av.z; As[ac + 3][ar] = av.w;
        *(float4*)&Bs[brr][bcc] = *(const float4*)(Bm + (size_t)(k0 + brr) * cH + n0 + bcc);
        __syncthreads();
#pragma unroll
        for (int kk = 0; kk < 16; ++kk) {
            float a[4], bv[4];
#pragma unroll
            for (int i = 0; i < 4; ++i) a[i] = As[kk][ty * 4 + i];
            *(float4*)bv = *(const float4*)&Bs[kk][tx * 4];
#pragma unroll
            for (int i = 0; i < 4; ++i)
#pragma unroll
                for (int j = 0; j < 4; ++j) acc[i][j] += a[i] * bv[j];
        }
        __syncthreads();
    }
#pragma unroll
    for (int i = 0; i < 4; ++i) {
        int rr = ty * 4 + i;
        int a = rowa[rr];
        if (a < 0) continue;
        int token = a >> 1;
        float w = wgt[a];
#pragma unroll
        for (int j = 0; j < 4; ++j) {
            int n = n0 + tx * 4 + j;
            atomicAdd(&out[(size_t)token * cH + n], w * (acc[i][j] + b_down[e * cH + n]));
        }
    }
}

extern "C" void kernel_launch(void* const* d_in, const int* in_sizes, int n_in,
                              void* d_out, int out_size, void* d_ws, size_t ws_size,
                              hipStream_t stream) {
    const float* x      = (const float*)d_in[0];
    const float* Wq     = (const float*)d_in[1];
    const float* bq     = (const float*)d_in[2];
    const float* Wk     = (const float*)d_in[3];
    const float* bk     = (const float*)d_in[4];
    const float* Wv     = (const float*)d_in[5];
    const float* bv     = (const float*)d_in[6];
    const float* Wo     = (const float*)d_in[7];
    const float* bo     = (const float*)d_in[8];
    const float* ln1g   = (const float*)d_in[9];
    const float* ln1b   = (const float*)d_in[10];
    const float* ln2g   = (const float*)d_in[11];
    const float* ln2b   = (const float*)d_in[12];
    const float* Wr     = (const float*)d_in[13];
    const float* br     = (const float*)d_in[14];
    const float* W_up   = (const float*)d_in[15];
    const float* b_up   = (const float*)d_in[16];
    const float* W_new  = (const float*)d_in[17];
    const float* b_new  = (const float*)d_in[18];
    const float* W_down = (const float*)d_in[19];
    const float* b_down = (const float*)d_in[20];

    float* out = (float*)d_out;
    float* ws  = (float*)d_ws;

    float* q    = ws + OFF_Q;
    float* k    = ws + OFF_K;
    float* v    = ws + OFF_V;
    float* ctx  = ws + OFF_CTX;
    float* tmp  = ws + OFF_TMP;
    float* attn = ws + OFF_ATTN;
    float* act  = ws + OFF_ACT;
    float* xl   = ws + OFF_XL;
    float* wgt  = ws + OFF_WGT;
    int* counts = (int*)(ws + OFF_COUNTS);
    int* lists  = (int*)(ws + OFF_LISTS);

    init_counts_kernel<<<1, 64, 0, stream>>>(counts);
    gemm_bias_kernel<<<dim3(cH / 64, cT / 64), 256, 0, stream>>>(x, Wq, bq, q, cT, cH, cH);
    gemm_bias_kernel<<<dim3(cH / 64, cT / 64), 256, 0, stream>>>(x, Wk, bk, k, cT, cH, cH);
    gemm_bias_kernel<<<dim3(cH / 64, cT / 64), 256, 0, stream>>>(x, Wv, bv, v, cT, cH, cH);
    attn_kernel<<<dim3(cS / 16, cNH, cB), 256, 0, stream>>>(q, k, v, ctx);
    gemm_bias_kernel<<<dim3(cH / 64, cT / 64), 256, 0, stream>>>(ctx, Wo, bo, tmp, cT, cH, cH);
    ln_fused_kernel<<<cT, 256, 0, stream>>>(tmp, x, ln1g, ln1b, ln2g, ln2b, attn, xl);
    router_kernel<<<cT / 4, 256, 0, stream>>>(xl, Wr, br, out + TH, wgt, counts, lists);
    copy_kernel<<<(int)(TH / 1024), 256, 0, stream>>>(attn, out);
    expert_up_kernel<<<dim3(cI / 64, cT / 64, cE), 256, 0, stream>>>(
        xl, W_up, b_up, W_new, b_new, counts, lists, act);
    expert_down_kernel<<<dim3(cH / 64, cT / 64, cE), 256, 0, stream>>>(
        act, W_down, b_down, counts, lists, wgt, out);
}

// Round 3
// 1392.641 us; speedup vs baseline: 1.9034x; 1.9034x over previous
//
#include <hip/hip_runtime.h>
#include <hip/hip_bf16.h>
#include <cmath>

// ---------------------------------------------------------------------------
// BertLayer + top-2 MoE, MI355X. Round 3: hybrid precision.
// fp32 (round-1 proven) for QKV/attention/Wo/LN/router -> exact expert
// selection; bf16 MFMA (m97 recipe) for the expert GEMMs (116 of 142 GFLOP).
// ---------------------------------------------------------------------------

constexpr int cB = 8, cS = 512, cH = 768, cNH = 12, cDH = 64, cI = 3072, cE = 8;
constexpr int cT = cB * cS;                       // 4096 tokens
constexpr size_t TH = (size_t)cT * cH;            // 3,145,728

typedef __hip_bfloat16 bf16;
typedef __attribute__((ext_vector_type(8))) short s8v;   // 8 bf16 = 4 VGPRs
typedef __attribute__((ext_vector_type(4))) float f4v;   // MFMA accumulator

// ---- workspace layout (float units) ---------------------------------------
constexpr size_t SZ_WEXP     = (size_t)cE * cI * cH / 2;        // 9,437,184
constexpr size_t OFF_WUP_T   = 0;                               // [E][I][H] bf16
constexpr size_t OFF_WNEW_T  = OFF_WUP_T + SZ_WEXP;
constexpr size_t OFF_WDOWN_T = OFF_WNEW_T + SZ_WEXP;            // [E][H][I] bf16
constexpr size_t OFF_QKV     = OFF_WDOWN_T + SZ_WEXP;           // q,k,v,tmp fp32
constexpr size_t OFF_CTX     = OFF_QKV + 4 * TH;                // ctx fp32
constexpr size_t OFF_ATTN    = OFF_CTX + TH;                    // attn fp32
constexpr size_t OFF_XLB     = OFF_ATTN + TH;                   // xl bf16
constexpr size_t OFF_WGT     = OFF_XLB + TH / 2;                // 2T fp32
constexpr size_t OFF_COUNTS  = OFF_WGT + 2 * cT;                // int[16]
constexpr size_t OFF_LISTS   = OFF_COUNTS + 16;                 // int[E*T]
// act (bf16, 8192 x 3072 = 12.58M float-units) aliases the q/k/v/tmp region,
// which is dead once ln_router has consumed tmp.

// ---------------------------------------------------------------------------
__device__ __forceinline__ void glds16(const void* g, void* l) {
    __builtin_amdgcn_global_load_lds(
        (const __attribute__((address_space(1))) unsigned int*)g,
        (__attribute__((address_space(3))) unsigned int*)l, 16, 0, 0);
}

__global__ void init_counts_kernel(int* __restrict__ counts) {
    if (threadIdx.x < cE) counts[threadIdx.x] = 0;
}

// src [z][R][C] fp32 -> dst [z][C][R] bf16   (R,C multiples of 64)
__global__ __launch_bounds__(256) void transpose_bf16_kernel(
    const float* __restrict__ src, bf16* __restrict__ dst, int R, int C) {
    __shared__ float tile[64][65];
    const size_t zb = (size_t)blockIdx.z * R * C;
    const int r0 = blockIdx.y * 64, c0 = blockIdx.x * 64;
    const int t = threadIdx.x;
    const int lr = t >> 4, lc = (t & 15) * 4;
#pragma unroll
    for (int i = 0; i < 4; ++i) {
        float4 v = *(const float4*)(src + zb + (size_t)(r0 + lr + i * 16) * C + c0 + lc);
        tile[lr + i * 16][lc + 0] = v.x; tile[lr + i * 16][lc + 1] = v.y;
        tile[lr + i * 16][lc + 2] = v.z; tile[lr + i * 16][lc + 3] = v.w;
    }
    __syncthreads();
#pragma unroll
    for (int i = 0; i < 4; ++i) {
        int cr = lr + i * 16;
        bf16 o[4];
#pragma unroll
        for (int j = 0; j < 4; ++j) o[j] = (bf16)tile[lc + j][cr];
        *(uint2*)(dst + zb + (size_t)(c0 + cr) * R + r0 + lc) = *(uint2*)o;
    }
}

// ---------------------------------------------------------------------------
// fp32 tile GEMM (round-1, proven): C[M,N] = A[M,K] @ B[K,N] + bias[N].
__global__ __launch_bounds__(256) void gemm_bias_kernel(
    const float* __restrict__ A, const float* __restrict__ B,
    const float* __restrict__ bias, float* __restrict__ C,
    int M, int N, int K) {
    __shared__ float As[16][65];
    __shared__ float Bs[16][64];
    const int tid = threadIdx.x;
    const int m0 = blockIdx.y * 64, n0 = blockIdx.x * 64;
    const int tx = tid & 15, ty = tid >> 4;
    const int ar = tid >> 2, ac = (tid & 3) * 4;
    const int br = tid >> 4, bc = (tid & 15) * 4;
    float acc[4][4] = {};
    for (int k0 = 0; k0 < K; k0 += 16) {
        float4 av = *(const float4*)(A + (size_t)(m0 + ar) * K + k0 + ac);
        As[ac + 0][ar] = av.x; As[ac + 1][ar] = av.y;
        As[ac + 2][ar] = av.z; As[ac + 3][ar] = av.w;
        *(float4*)&Bs[br][bc] = *(const float4*)(B + (size_t)(k0 + br) * N + n0 + bc);
        __syncthreads();
#pragma unroll
        for (int kk = 0; kk < 16; ++kk) {
            float a[4], bv[4];
#pragma unroll
            for (int i = 0; i < 4; ++i) a[i] = As[kk][ty * 4 + i];
            *(float4*)bv = *(const float4*)&Bs[kk][tx * 4];
#pragma unroll
            for (int i = 0; i < 4; ++i)
#pragma unroll
                for (int j = 0; j < 4; ++j) acc[i][j] += a[i] * bv[j];
        }
        __syncthreads();
    }
#pragma unroll
    for (int i = 0; i < 4; ++i) {
        float4 o;
        o.x = acc[i][0] + bias[n0 + tx * 4 + 0];
        o.y = acc[i][1] + bias[n0 + tx * 4 + 1];
        o.z = acc[i][2] + bias[n0 + tx * 4 + 2];
        o.w = acc[i][3] + bias[n0 + tx * 4 + 3];
        *(float4*)(C + (size_t)(m0 + ty * 4 + i) * N + n0 + tx * 4) = o;
    }
}

// ---------------------------------------------------------------------------
// fp32 fused attention (round-1, proven). One block per (q16, head, batch).
__global__ __launch_bounds__(256) void attn_kernel(
    const float* __restrict__ q, const float* __restrict__ k,
    const float* __restrict__ v, float* __restrict__ ctx) {
    __shared__ float sQ[16][68];
    __shared__ float sKV[64][68];
    __shared__ float sP[16][516];
    const int qt = blockIdx.x, h = blockIdx.y, b = blockIdx.z;
    const int tid = threadIdx.x;
    {
        int r = tid >> 4, d = (tid & 15) * 4;
        *(float4*)&sQ[r][d] =
            *(const float4*)(q + (size_t)(b * cS + qt * 16 + r) * cH + h * cDH + d);
    }
    __syncthreads();
    const int r = tid & 15, cb = tid >> 4;
    for (int ct = 0; ct < 8; ++ct) {
#pragma unroll
        for (int i = 0; i < 4; ++i) {
            int c = (tid >> 4) + i * 16, d = (tid & 15) * 4;
            *(float4*)&sKV[c][d] =
                *(const float4*)(k + (size_t)(b * cS + ct * 64 + c) * cH + h * cDH + d);
        }
        __syncthreads();
        float acc[4] = {0.f, 0.f, 0.f, 0.f};
#pragma unroll
        for (int d = 0; d < 64; ++d) {
            float qv = sQ[r][d];
            acc[0] += qv * sKV[cb][d];
            acc[1] += qv * sKV[cb + 16][d];
            acc[2] += qv * sKV[cb + 32][d];
            acc[3] += qv * sKV[cb + 48][d];
        }
#pragma unroll
        for (int j = 0; j < 4; ++j) sP[r][ct * 64 + cb + 16 * j] = acc[j] * 0.125f;
        __syncthreads();
    }
    {
        const int wave = tid >> 6, lane = tid & 63;
        for (int rr = 0; rr < 4; ++rr) {
            int row = wave * 4 + rr;
            float vals[8], m = -1e30f;
#pragma unroll
            for (int i = 0; i < 8; ++i) {
                vals[i] = sP[row][lane + 64 * i];
                m = fmaxf(m, vals[i]);
            }
#pragma unroll
            for (int o = 32; o; o >>= 1) m = fmaxf(m, __shfl_xor(m, o));
            float s = 0.f;
#pragma unroll
            for (int i = 0; i < 8; ++i) { vals[i] = __expf(vals[i] - m); s += vals[i]; }
#pragma unroll
            for (int o = 32; o; o >>= 1) s += __shfl_xor(s, o);
            float inv = 1.0f / s;
#pragma unroll
            for (int i = 0; i < 8; ++i) sP[row][lane + 64 * i] = vals[i] * inv;
        }
    }
    __syncthreads();
    float o[4] = {0.f, 0.f, 0.f, 0.f};
    for (int vt = 0; vt < 8; ++vt) {
#pragma unroll
        for (int i = 0; i < 4; ++i) {
            int c = (tid >> 4) + i * 16, d = (tid & 15) * 4;
            *(float4*)&sKV[c][d] =
                *(const float4*)(v + (size_t)(b * cS + vt * 64 + c) * cH + h * cDH + d);
        }
        __syncthreads();
#pragma unroll
        for (int kk = 0; kk < 64; ++kk) {
            float p = sP[r][vt * 64 + kk];
            o[0] += p * sKV[kk][cb];
            o[1] += p * sKV[kk][cb + 16];
            o[2] += p * sKV[kk][cb + 32];
            o[3] += p * sKV[kk][cb + 48];
        }
        __syncthreads();
    }
#pragma unroll
    for (int j = 0; j < 4; ++j)
        ctx[(size_t)(b * cS + qt * 16 + r) * cH + h * cDH + cb + 16 * j] = o[j];
}

__device__ __forceinline__ float block_reduce_sum(float v, float* red) {
#pragma unroll
    for (int o = 32; o; o >>= 1) v += __shfl_xor(v, o);
    __syncthreads();
    if ((threadIdx.x & 63) == 0) red[threadIdx.x >> 6] = v;
    __syncthreads();
    return red[0] + red[1] + red[2] + red[3];
}

// ---------------------------------------------------------------------------
// LN1 + LN2 + router, all fp32 (selection-exact). One block per token.
// Outputs: attn fp32, xl bf16 (expert input), router logits (to out tail),
// gate weights, per-expert lists.
__global__ __launch_bounds__(256) void ln_router_kernel(
    const float* __restrict__ dense, const float* __restrict__ resid,
    const float* __restrict__ g1, const float* __restrict__ b1,
    const float* __restrict__ g2, const float* __restrict__ b2,
    const float* __restrict__ Wr, const float* __restrict__ br,
    float* __restrict__ attn_out, bf16* __restrict__ xlb,
    float* __restrict__ out_logits, float* __restrict__ wgt,
    int* __restrict__ counts, int* __restrict__ lists) {
    __shared__ float red[4];
    __shared__ float lred[4][8];
    const int t = blockIdx.x, tid = threadIdx.x;
    const size_t base = (size_t)t * cH;
    float v[3], s = 0.f;
#pragma unroll
    for (int i = 0; i < 3; ++i) {
        v[i] = dense[base + tid + 256 * i] + resid[base + tid + 256 * i];
        s += v[i];
    }
    const float mean = block_reduce_sum(s, red) * (1.0f / cH);
    float vs = 0.f;
#pragma unroll
    for (int i = 0; i < 3; ++i) { float d = v[i] - mean; vs += d * d; }
    const float rstd = rsqrtf(block_reduce_sum(vs, red) * (1.0f / cH) + 1e-12f);
    float a[3], s2 = 0.f;
#pragma unroll
    for (int i = 0; i < 3; ++i) {
        a[i] = (v[i] - mean) * rstd * g1[tid + 256 * i] + b1[tid + 256 * i];
        attn_out[base + tid + 256 * i] = a[i];
        s2 += a[i];
    }
    const float mean2 = block_reduce_sum(s2, red) * (1.0f / cH);
    float vs2 = 0.f;
#pragma unroll
    for (int i = 0; i < 3; ++i) { float d = a[i] - mean2; vs2 += d * d; }
    const float rstd2 = rsqrtf(block_reduce_sum(vs2, red) * (1.0f / cH) + 1e-12f);
    float xl[3];
#pragma unroll
    for (int i = 0; i < 3; ++i) {
        xl[i] = (a[i] - mean2) * rstd2 * g2[tid + 256 * i] + b2[tid + 256 * i];
        xlb[base + tid + 256 * i] = (bf16)xl[i];
    }
    // router logits (fp32, selection-exact vs fp32 reference)
    float lg[cE] = {};
#pragma unroll
    for (int i = 0; i < 3; ++i) {
        const float* wr = Wr + (size_t)(tid + 256 * i) * cE;
#pragma unroll
        for (int e = 0; e < cE; ++e) lg[e] += xl[i] * wr[e];
    }
#pragma unroll
    for (int e = 0; e < cE; ++e)
#pragma unroll
        for (int o = 32; o; o >>= 1) lg[e] += __shfl_xor(lg[e], o);
    if ((tid & 63) == 0)
#pragma unroll
        for (int e = 0; e < cE; ++e) lred[tid >> 6][e] = lg[e];
    __syncthreads();
    if (tid == 0) {
        float logits[cE];
#pragma unroll
        for (int e = 0; e < cE; ++e) {
            logits[e] = lred[0][e] + lred[1][e] + lred[2][e] + lred[3][e] + br[e];
            out_logits[(size_t)t * cE + e] = logits[e];
        }
        int i0 = 0;
        for (int e = 1; e < cE; ++e) if (logits[e] > logits[i0]) i0 = e;
        int i1 = (i0 == 0) ? 1 : 0;
        for (int e = 0; e < cE; ++e)
            if (e != i0 && logits[e] > logits[i1]) i1 = e;
        float e1 = __expf(logits[i1] - logits[i0]);
        float w0 = 1.0f / (1.0f + e1);
        float w1 = e1 * w0;
        wgt[t * 2 + 0] = w0;
        wgt[t * 2 + 1] = w1;
        int p0 = atomicAdd(&counts[i0], 1);
        lists[i0 * cT + p0] = t * 2 + 0;
        int p1 = atomicAdd(&counts[i1], 1);
        lists[i1 * cT + p1] = t * 2 + 1;
    }
}

__global__ __launch_bounds__(256) void copy_kernel(
    const float* __restrict__ src, float* __restrict__ dst) {
    size_t i = ((size_t)blockIdx.x * 256 + threadIdx.x) * 4;
    *(float4*)(dst + i) = *(const float4*)(src + i);
}

// ---------------------------------------------------------------------------
// bf16 MFMA expert GEMMs (m97 recipe: 128x128 tile, BK=32, glds16 staging).
// ---------------------------------------------------------------------------

// act[a,:] = gelu(xl@W_up[e]+b_up) * (xl@W_new[e]+b_new), gathered rows.
__global__ __launch_bounds__(256) void expert_up_mfma_kernel(
    const bf16* __restrict__ xlb,
    const bf16* __restrict__ WupT, const bf16* __restrict__ WnewT,
    const float* __restrict__ b_up, const float* __restrict__ b_new,
    const int* __restrict__ counts, const int* __restrict__ lists,
    bf16* __restrict__ act) {
    const int e = blockIdx.z;
    const int cnt = counts[e];
    const int m0 = blockIdx.y * 128;
    if (m0 >= cnt) return;
    const int n0 = blockIdx.x * 128;
    __shared__ short sA[128 * 32], sB1[128 * 32], sB2[128 * 32];
    __shared__ int rowa[128];
    const int t = threadIdx.x;
    if (t < 128) {
        int idx = m0 + t;
        rowa[t] = (idx < cnt) ? lists[e * cT + idx] : -1;
    }
    __syncthreads();
    const int lane = t & 63, w = t >> 6;
    const int wm = (w >> 1) * 64, wn = (w & 1) * 64;
    const int rA0 = t >> 2, kc8 = (t & 3) * 8;
    int a0 = rowa[rA0], a1 = rowa[rA0 + 64];
    const bf16* gA0 = xlb + (size_t)(a0 < 0 ? 0 : (a0 >> 1)) * cH + kc8;
    const bf16* gA1 = xlb + (size_t)(a1 < 0 ? 0 : (a1 >> 1)) * cH + kc8;
    const bf16* B1 = WupT + (size_t)e * cI * cH;
    const bf16* B2 = WnewT + (size_t)e * cI * cH;
    const bf16* gB10 = B1 + (size_t)(n0 + rA0) * cH + kc8;
    const bf16* gB11 = B1 + (size_t)(n0 + rA0 + 64) * cH + kc8;
    const bf16* gB20 = B2 + (size_t)(n0 + rA0) * cH + kc8;
    const bf16* gB21 = B2 + (size_t)(n0 + rA0 + 64) * cH + kc8;
    short* dA0  = sA  + t * 8;      short* dA1  = sA  + (t + 256) * 8;
    short* dB10 = sB1 + t * 8;      short* dB11 = sB1 + (t + 256) * 8;
    short* dB20 = sB2 + t * 8;      short* dB21 = sB2 + (t + 256) * 8;
    f4v zero = {0.f, 0.f, 0.f, 0.f};
    f4v acc1[4][4], acc2[4][4];
#pragma unroll
    for (int i = 0; i < 4; ++i)
#pragma unroll
        for (int j = 0; j < 4; ++j) { acc1[i][j] = zero; acc2[i][j] = zero; }
    const int fr = lane & 15, kg = (lane >> 4) * 8;
    for (int kk = 0; kk < cH; kk += 32) {
        glds16(gA0, dA0);   glds16(gA1, dA1);
        glds16(gB10, dB10); glds16(gB11, dB11);
        glds16(gB20, dB20); glds16(gB21, dB21);
        __syncthreads();
        s8v af[4], bf1[4], bf2[4];
#pragma unroll
        for (int i = 0; i < 4; ++i) {
            af[i]  = *(const s8v*)(sA  + (wm + i * 16 + fr) * 32 + kg);
            bf1[i] = *(const s8v*)(sB1 + (wn + i * 16 + fr) * 32 + kg);
            bf2[i] = *(const s8v*)(sB2 + (wn + i * 16 + fr) * 32 + kg);
        }
#pragma unroll
        for (int mi = 0; mi < 4; ++mi)
#pragma unroll
            for (int ni = 0; ni < 4; ++ni) {
                acc1[mi][ni] = __builtin_amdgcn_mfma_f32_16x16x32_bf16(
                    af[mi], bf1[ni], acc1[mi][ni], 0, 0, 0);
                acc2[mi][ni] = __builtin_amdgcn_mfma_f32_16x16x32_bf16(
                    af[mi], bf2[ni], acc2[mi][ni], 0, 0, 0);
            }
        __syncthreads();
        gA0 += 32; gA1 += 32; gB10 += 32; gB11 += 32; gB20 += 32; gB21 += 32;
    }
    const int cn = lane & 15, rq = (lane >> 4) * 4;
#pragma unroll
    for (int mi = 0; mi < 4; ++mi)
#pragma unroll
        for (int r = 0; r < 4; ++r) {
            int ml = wm + mi * 16 + rq + r;
            int a = rowa[ml];
            if (a < 0) continue;
            bf16* orow = act + (size_t)a * cI + n0 + wn;
#pragma unroll
            for (int ni = 0; ni < 4; ++ni) {
                int nl = ni * 16 + cn;
                float up = acc1[mi][ni][r] + b_up[e * cI + n0 + wn + nl];
                float nw = acc2[mi][ni][r] + b_new[e * cI + n0 + wn + nl];
                float g = 0.5f * up * (1.0f + erff(up * 0.70710678118654752f));
                orow[nl] = (bf16)(g * nw);
            }
        }
}

// out[token,:] += w[a]*(act[a,:]@W_downT[e]+b_down[e])  (fp32 atomicAdd)
__global__ __launch_bounds__(256) void expert_down_mfma_kernel(
    const bf16* __restrict__ act, const bf16* __restrict__ WdownT,
    const float* __restrict__ b_down,
    const int* __restrict__ counts, const int* __restrict__ lists,
    const float* __restrict__ wgt, float* __restrict__ out) {
    const int e = blockIdx.z;
    const int cnt = counts[e];
    const int m0 = blockIdx.y * 128;
    if (m0 >= cnt) return;
    const int n0 = blockIdx.x * 128;
    __shared__ short sA[128 * 32], sB[128 * 32];
    __shared__ int rowa[128];
    const int t = threadIdx.x;
    if (t < 128) {
        int idx = m0 + t;
        rowa[t] = (idx < cnt) ? lists[e * cT + idx] : -1;
    }
    __syncthreads();
    const int lane = t & 63, w = t >> 6;
    const int wm = (w >> 1) * 64, wn = (w & 1) * 64;
    const int rA0 = t >> 2, kc8 = (t & 3) * 8;
    int a0 = rowa[rA0], a1 = rowa[rA0 + 64];
    const bf16* gA0 = act + (size_t)(a0 < 0 ? 0 : a0) * cI + kc8;
    const bf16* gA1 = act + (size_t)(a1 < 0 ? 0 : a1) * cI + kc8;
    const bf16* BT = WdownT + (size_t)e * cH * cI;
    const bf16* gB0 = BT + (size_t)(n0 + rA0) * cI + kc8;
    const bf16* gB1 = BT + (size_t)(n0 + rA0 + 64) * cI + kc8;
    short* dA0 = sA + t * 8;       short* dA1 = sA + (t + 256) * 8;
    short* dB0 = sB + t * 8;       short* dB1 = sB + (t + 256) * 8;
    f4v zero = {0.f, 0.f, 0.f, 0.f};
    f4v acc[4][4];
#pragma unroll
    for (int i = 0; i < 4; ++i)
#pragma unroll
        for (int j = 0; j < 4; ++j) acc[i][j] = zero;
    const int fr = lane & 15, kg = (lane >> 4) * 8;
    for (int kk = 0; kk < cI; kk += 32) {
        glds16(gA0, dA0); glds16(gA1, dA1);
        glds16(gB0, dB0); glds16(gB1, dB1);
        __syncthreads();
        s8v af[4], bf[4];
#pragma unroll
        for (int i = 0; i < 4; ++i) af[i] = *(const s8v*)(sA + (wm + i * 16 + fr) * 32 + kg);
#pragma unroll
        for (int i = 0; i < 4; ++i) bf[i] = *(const s8v*)(sB + (wn + i * 16 + fr) * 32 + kg);
#pragma unroll
        for (int mi = 0; mi < 4; ++mi)
#pragma unroll
            for (int ni = 0; ni < 4; ++ni)
                acc[mi][ni] = __builtin_amdgcn_mfma_f32_16x16x32_bf16(
                    af[mi], bf[ni], acc[mi][ni], 0, 0, 0);
        __syncthreads();
        gA0 += 32; gA1 += 32; gB0 += 32; gB1 += 32;
    }
    const int cn = lane & 15, rq = (lane >> 4) * 4;
#pragma unroll
    for (int mi = 0; mi < 4; ++mi)
#pragma unroll
        for (int r = 0; r < 4; ++r) {
            int ml = wm + mi * 16 + rq + r;
            int a = rowa[ml];
            if (a < 0) continue;
            int token = a >> 1;
            float wv = wgt[a];
#pragma unroll
            for (int ni = 0; ni < 4; ++ni) {
                int n = n0 + wn + ni * 16 + cn;
                atomicAdd(&out[(size_t)token * cH + n],
                          wv * (acc[mi][ni][r] + b_down[e * cH + n]));
            }
        }
}

// ---------------------------------------------------------------------------
extern "C" void kernel_launch(void* const* d_in, const int* in_sizes, int n_in,
                              void* d_out, int out_size, void* d_ws, size_t ws_size,
                              hipStream_t stream) {
    const float* x      = (const float*)d_in[0];
    const float* Wq     = (const float*)d_in[1];
    const float* bq     = (const float*)d_in[2];
    const float* Wk     = (const float*)d_in[3];
    const float* bk     = (const float*)d_in[4];
    const float* Wv     = (const float*)d_in[5];
    const float* bv     = (const float*)d_in[6];
    const float* Wo     = (const float*)d_in[7];
    const float* bo     = (const float*)d_in[8];
    const float* ln1g   = (const float*)d_in[9];
    const float* ln1b   = (const float*)d_in[10];
    const float* ln2g   = (const float*)d_in[11];
    const float* ln2b   = (const float*)d_in[12];
    const float* Wr     = (const float*)d_in[13];
    const float* br     = (const float*)d_in[14];
    const float* W_up   = (const float*)d_in[15];
    const float* b_up   = (const float*)d_in[16];
    const float* W_new  = (const float*)d_in[17];
    const float* b_new  = (const float*)d_in[18];
    const float* W_down = (const float*)d_in[19];
    const float* b_down = (const float*)d_in[20];

    float* out = (float*)d_out;
    float* ws  = (float*)d_ws;

    bf16* WupT   = (bf16*)(ws + OFF_WUP_T);
    bf16* WnewT  = (bf16*)(ws + OFF_WNEW_T);
    bf16* WdownT = (bf16*)(ws + OFF_WDOWN_T);
    float* q     = ws + OFF_QKV;
    float* k     = ws + OFF_QKV + TH;
    float* v     = ws + OFF_QKV + 2 * TH;
    float* tmp   = ws + OFF_QKV + 3 * TH;
    bf16* act    = (bf16*)(ws + OFF_QKV);   // aliases q/k/v/tmp (dead by then)
    float* ctx   = ws + OFF_CTX;
    float* attn  = ws + OFF_ATTN;
    bf16* xlb    = (bf16*)(ws + OFF_XLB);
    float* wgt   = ws + OFF_WGT;
    int* counts  = (int*)(ws + OFF_COUNTS);
    int* lists   = (int*)(ws + OFF_LISTS);

    init_counts_kernel<<<1, 64, 0, stream>>>(counts);

    // expert weight transpose+convert (fp32 [H][I] -> bf16 [I][H] etc.)
    transpose_bf16_kernel<<<dim3(48, 12, cE), 256, 0, stream>>>(W_up, WupT, cH, cI);
    transpose_bf16_kernel<<<dim3(48, 12, cE), 256, 0, stream>>>(W_new, WnewT, cH, cI);
    transpose_bf16_kernel<<<dim3(12, 48, cE), 256, 0, stream>>>(W_down, WdownT, cI, cH);

    // fp32 pre-router path (selection-exact)
    gemm_bias_kernel<<<dim3(cH / 64, cT / 64), 256, 0, stream>>>(x, Wq, bq, q, cT, cH, cH);
    gemm_bias_kernel<<<dim3(cH / 64, cT / 64), 256, 0, stream>>>(x, Wk, bk, k, cT, cH, cH);
    gemm_bias_kernel<<<dim3(cH / 64, cT / 64), 256, 0, stream>>>(x, Wv, bv, v, cT, cH, cH);
    attn_kernel<<<dim3(cS / 16, cNH, cB), 256, 0, stream>>>(q, k, v, ctx);
    gemm_bias_kernel<<<dim3(cH / 64, cT / 64), 256, 0, stream>>>(ctx, Wo, bo, tmp, cT, cH, cH);
    ln_router_kernel<<<cT, 256, 0, stream>>>(
        tmp, x, ln1g, ln1b, ln2g, ln2b, Wr, br,
        attn, xlb, out + TH, wgt, counts, lists);

    // out = attention_output (residual base), then bf16 MFMA experts
    copy_kernel<<<(int)(TH / 1024), 256, 0, stream>>>(attn, out);
    expert_up_mfma_kernel<<<dim3(cI / 128, cT / 128, cE), 256, 0, stream>>>(
        xlb, WupT, WnewT, b_up, b_new, counts, lists, act);
    expert_down_mfma_kernel<<<dim3(cH / 128, cT / 128, cE), 256, 0, stream>>>(
        act, WdownT, b_down, counts, lists, wgt, out);
}

// Round 4
// 1204.842 us; speedup vs baseline: 2.2000x; 1.1559x over previous
//
#include <hip/hip_runtime.h>
#include <hip/hip_bf16.h>
#include <cmath>

// ---------------------------------------------------------------------------
// BertLayer + top-2 MoE, MI355X. Round 4: flash-style fp32 attention
// (64-row tiles, online softmax, b128 LDS), fused QKV launch, copy folded
// into ln_router. Experts stay bf16 MFMA (round-3 proven).
// ---------------------------------------------------------------------------

constexpr int cB = 8, cS = 512, cH = 768, cNH = 12, cDH = 64, cI = 3072, cE = 8;
constexpr int cT = cB * cS;                       // 4096 tokens
constexpr size_t TH = (size_t)cT * cH;            // 3,145,728

typedef __hip_bfloat16 bf16;
typedef __attribute__((ext_vector_type(8))) short s8v;   // 8 bf16 = 4 VGPRs
typedef __attribute__((ext_vector_type(4))) float f4v;   // MFMA accumulator

// ---- workspace layout (float units) ---------------------------------------
constexpr size_t SZ_WEXP     = (size_t)cE * cI * cH / 2;        // 9,437,184
constexpr size_t OFF_WUP_T   = 0;                               // [E][I][H] bf16
constexpr size_t OFF_WNEW_T  = OFF_WUP_T + SZ_WEXP;
constexpr size_t OFF_WDOWN_T = OFF_WNEW_T + SZ_WEXP;            // [E][H][I] bf16
constexpr size_t OFF_QKV     = OFF_WDOWN_T + SZ_WEXP;           // q,k,v,tmp fp32
constexpr size_t OFF_CTX     = OFF_QKV + 4 * TH;                // ctx fp32
constexpr size_t OFF_XLB     = OFF_CTX + TH;                    // xl bf16
constexpr size_t OFF_WGT     = OFF_XLB + TH / 2;                // 2T fp32
constexpr size_t OFF_COUNTS  = OFF_WGT + 2 * cT;                // int[16]
constexpr size_t OFF_LISTS   = OFF_COUNTS + 16;                 // int[E*T]
// act (bf16) aliases q/k/v/tmp region (dead once ln_router consumed tmp).

// ---------------------------------------------------------------------------
__device__ __forceinline__ void glds16(const void* g, void* l) {
    __builtin_amdgcn_global_load_lds(
        (const __attribute__((address_space(1))) unsigned int*)g,
        (__attribute__((address_space(3))) unsigned int*)l, 16, 0, 0);
}

__global__ void init_counts_kernel(int* __restrict__ counts) {
    if (threadIdx.x < cE) counts[threadIdx.x] = 0;
}

// src [z][R][C] fp32 -> dst [z][C][R] bf16   (R,C multiples of 64)
__global__ __launch_bounds__(256) void transpose_bf16_kernel(
    const float* __restrict__ src, bf16* __restrict__ dst, int R, int C) {
    __shared__ float tile[64][65];
    const size_t zb = (size_t)blockIdx.z * R * C;
    const int r0 = blockIdx.y * 64, c0 = blockIdx.x * 64;
    const int t = threadIdx.x;
    const int lr = t >> 4, lc = (t & 15) * 4;
#pragma unroll
    for (int i = 0; i < 4; ++i) {
        float4 v = *(const float4*)(src + zb + (size_t)(r0 + lr + i * 16) * C + c0 + lc);
        tile[lr + i * 16][lc + 0] = v.x; tile[lr + i * 16][lc + 1] = v.y;
        tile[lr + i * 16][lc + 2] = v.z; tile[lr + i * 16][lc + 3] = v.w;
    }
    __syncthreads();
#pragma unroll
    for (int i = 0; i < 4; ++i) {
        int cr = lr + i * 16;
        bf16 o[4];
#pragma unroll
        for (int j = 0; j < 4; ++j) o[j] = (bf16)tile[lc + j][cr];
        *(uint2*)(dst + zb + (size_t)(c0 + cr) * R + r0 + lc) = *(uint2*)o;
    }
}

// ---------------------------------------------------------------------------
// fp32 tile GEMM: C[M,N] = A[M,K] @ B[K,N] + bias[N] (64x64 tile).
__device__ __forceinline__ void gemm_body(
    const float* __restrict__ A, const float* __restrict__ B,
    const float* __restrict__ bias, float* __restrict__ C,
    int N, int K, int m0, int n0) {
    __shared__ float As[16][65];
    __shared__ float Bs[16][64];
    const int tid = threadIdx.x;
    const int tx = tid & 15, ty = tid >> 4;
    const int ar = tid >> 2, ac = (tid & 3) * 4;
    const int br = tid >> 4, bc = (tid & 15) * 4;
    float acc[4][4] = {};
    for (int k0 = 0; k0 < K; k0 += 16) {
        float4 av = *(const float4*)(A + (size_t)(m0 + ar) * K + k0 + ac);
        As[ac + 0][ar] = av.x; As[ac + 1][ar] = av.y;
        As[ac + 2][ar] = av.z; As[ac + 3][ar] = av.w;
        *(float4*)&Bs[br][bc] = *(const float4*)(B + (size_t)(k0 + br) * N + n0 + bc);
        __syncthreads();
#pragma unroll
        for (int kk = 0; kk < 16; ++kk) {
            float a[4], bv[4];
#pragma unroll
            for (int i = 0; i < 4; ++i) a[i] = As[kk][ty * 4 + i];
            *(float4*)bv = *(const float4*)&Bs[kk][tx * 4];
#pragma unroll
            for (int i = 0; i < 4; ++i)
#pragma unroll
                for (int j = 0; j < 4; ++j) acc[i][j] += a[i] * bv[j];
        }
        __syncthreads();
    }
#pragma unroll
    for (int i = 0; i < 4; ++i) {
        float4 o;
        o.x = acc[i][0] + bias[n0 + tx * 4 + 0];
        o.y = acc[i][1] + bias[n0 + tx * 4 + 1];
        o.z = acc[i][2] + bias[n0 + tx * 4 + 2];
        o.w = acc[i][3] + bias[n0 + tx * 4 + 3];
        *(float4*)(C + (size_t)(m0 + ty * 4 + i) * N + n0 + tx * 4) = o;
    }
}

// QKV: one launch, grid.z selects W/bias/output (shared A stays hot in L2).
__global__ __launch_bounds__(256) void gemm_qkv_kernel(
    const float* __restrict__ A,
    const float* __restrict__ Wq, const float* __restrict__ Wk,
    const float* __restrict__ Wv,
    const float* __restrict__ bq, const float* __restrict__ bk,
    const float* __restrict__ bv,
    float* __restrict__ q, float* __restrict__ k, float* __restrict__ v) {
    const int z = blockIdx.z;
    const float* B = (z == 0) ? Wq : (z == 1) ? Wk : Wv;
    const float* bias = (z == 0) ? bq : (z == 1) ? bk : bv;
    float* C = (z == 0) ? q : (z == 1) ? k : v;
    gemm_body(A, B, bias, C, cH, cH, blockIdx.y * 64, blockIdx.x * 64);
}

__global__ __launch_bounds__(256) void gemm_bias_kernel(
    const float* __restrict__ A, const float* __restrict__ B,
    const float* __restrict__ bias, float* __restrict__ C,
    int M, int N, int K) {
    gemm_body(A, B, bias, C, N, K, blockIdx.y * 64, blockIdx.x * 64);
}

// ---------------------------------------------------------------------------
// Flash-style fp32 attention. Block = 64 q-rows x 1 head x 1 batch.
// Online softmax; K/V share one LDS buffer; all LDS traffic is b128.
__global__ __launch_bounds__(256) void attn_kernel(
    const float* __restrict__ q, const float* __restrict__ k,
    const float* __restrict__ v, float* __restrict__ ctx) {
    __shared__ float sQ[64][68];
    __shared__ float sKV[64][68];
    __shared__ float sS[64][68];
    __shared__ float sM[64], sL[64], sAl[64];
    const int q0 = blockIdx.x * 64, h = blockIdx.y, b = blockIdx.z;
    const int t = threadIdx.x;
    const int lr = t >> 2, lq = (t & 3) * 16;       // loader: row, 16-col group
    // load Q tile, pre-scaled by 1/sqrt(DH)=0.125
    {
        const float* gq = q + (size_t)(b * cS + q0 + lr) * cH + h * cDH + lq;
#pragma unroll
        for (int j = 0; j < 4; ++j) {
            float4 x = *(const float4*)(gq + j * 4);
            x.x *= 0.125f; x.y *= 0.125f; x.z *= 0.125f; x.w *= 0.125f;
            *(float4*)&sQ[lr][lq + j * 4] = x;
        }
    }
    if (t < 64) { sM[t] = -1e30f; sL[t] = 0.f; }

    // QK mapping: rows rr..rr+3, cols c0+{0,16,32,48}
    const int c0 = t & 15, rr = (t >> 4) * 4;
    // PV / output mapping: rows rp..rp+3, one float4 at d4
    const int d4 = (t & 15) * 4, rp = (t >> 4) * 4;
    // softmax mapping: row sr, 16 cols at sc
    const int sr = t >> 2, sc = (t & 3) * 16;

    float4 o_acc[4];
#pragma unroll
    for (int i = 0; i < 4; ++i) o_acc[i] = make_float4(0.f, 0.f, 0.f, 0.f);

    for (int kt = 0; kt < 8; ++kt) {
        // K tile -> regs (before sync: global reads only)
        float4 kreg[4];
        {
            const float* gk = k + (size_t)(b * cS + kt * 64 + lr) * cH + h * cDH + lq;
#pragma unroll
            for (int j = 0; j < 4; ++j) kreg[j] = *(const float4*)(gk + j * 4);
        }
        __syncthreads();                 // prev PV done with sKV/sS
#pragma unroll
        for (int j = 0; j < 4; ++j) *(float4*)&sKV[lr][lq + j * 4] = kreg[j];
        __syncthreads();                 // K visible (Q visible from 1st pass)
        // ---- S = Q K^T -------------------------------------------------
        float accS[4][4] = {};
#pragma unroll
        for (int d = 0; d < 64; d += 4) {
            float4 qv[4], kv[4];
#pragma unroll
            for (int i = 0; i < 4; ++i) qv[i] = *(const float4*)&sQ[rr + i][d];
#pragma unroll
            for (int j = 0; j < 4; ++j) kv[j] = *(const float4*)&sKV[c0 + 16 * j][d];
#pragma unroll
            for (int i = 0; i < 4; ++i)
#pragma unroll
                for (int j = 0; j < 4; ++j)
                    accS[i][j] += qv[i].x * kv[j].x + qv[i].y * kv[j].y +
                                  qv[i].z * kv[j].z + qv[i].w * kv[j].w;
        }
#pragma unroll
        for (int i = 0; i < 4; ++i)
#pragma unroll
            for (int j = 0; j < 4; ++j) sS[rr + i][c0 + 16 * j] = accS[i][j];
        // V tile -> regs (global latency hides behind softmax below)
        float4 vreg[4];
        {
            const float* gv = v + (size_t)(b * cS + kt * 64 + lr) * cH + h * cDH + lq;
#pragma unroll
            for (int j = 0; j < 4; ++j) vreg[j] = *(const float4*)(gv + j * 4);
        }
        __syncthreads();                 // S visible; QK done reading sKV
        // ---- online softmax (4 lanes per row) --------------------------
        {
            float4 s[4];
#pragma unroll
            for (int j = 0; j < 4; ++j) s[j] = *(const float4*)&sS[sr][sc + j * 4];
            float m = -1e30f;
#pragma unroll
            for (int j = 0; j < 4; ++j)
                m = fmaxf(m, fmaxf(fmaxf(s[j].x, s[j].y), fmaxf(s[j].z, s[j].w)));
            m = fmaxf(m, __shfl_xor(m, 1));
            m = fmaxf(m, __shfl_xor(m, 2));
            float m_old = sM[sr];
            float m_new = fmaxf(m_old, m);
            float sum = 0.f;
#pragma unroll
            for (int j = 0; j < 4; ++j) {
                s[j].x = __expf(s[j].x - m_new); s[j].y = __expf(s[j].y - m_new);
                s[j].z = __expf(s[j].z - m_new); s[j].w = __expf(s[j].w - m_new);
                sum += s[j].x + s[j].y + s[j].z + s[j].w;
                *(float4*)&sS[sr][sc + j * 4] = s[j];
            }
            sum += __shfl_xor(sum, 1);
            sum += __shfl_xor(sum, 2);
            if ((t & 3) == 0) {
                float alpha = __expf(m_old - m_new);
                sAl[sr] = alpha;
                sM[sr] = m_new;
                sL[sr] = sL[sr] * alpha + sum;
            }
        }
#pragma unroll
        for (int j = 0; j < 4; ++j) *(float4*)&sKV[lr][lq + j * 4] = vreg[j];
        __syncthreads();                 // P, V, alpha visible
        // ---- O = O*alpha + P V -----------------------------------------
#pragma unroll
        for (int i = 0; i < 4; ++i) {
            float al = sAl[rp + i];
            o_acc[i].x *= al; o_acc[i].y *= al; o_acc[i].z *= al; o_acc[i].w *= al;
        }
        for (int kk4 = 0; kk4 < 64; kk4 += 4) {
            float4 pv[4], vv[4];
#pragma unroll
            for (int i = 0; i < 4; ++i) pv[i] = *(const float4*)&sS[rp + i][kk4];
#pragma unroll
            for (int j = 0; j < 4; ++j) vv[j] = *(const float4*)&sKV[kk4 + j][d4];
#pragma unroll
            for (int i = 0; i < 4; ++i) {
                o_acc[i].x += pv[i].x * vv[0].x + pv[i].y * vv[1].x +
                              pv[i].z * vv[2].x + pv[i].w * vv[3].x;
                o_acc[i].y += pv[i].x * vv[0].y + pv[i].y * vv[1].y +
                              pv[i].z * vv[2].y + pv[i].w * vv[3].y;
                o_acc[i].z += pv[i].x * vv[0].z + pv[i].y * vv[1].z +
                              pv[i].z * vv[2].z + pv[i].w * vv[3].z;
                o_acc[i].w += pv[i].x * vv[0].w + pv[i].y * vv[1].w +
                              pv[i].z * vv[2].w + pv[i].w * vv[3].w;
            }
        }
    }
    __syncthreads();
#pragma unroll
    for (int i = 0; i < 4; ++i) {
        float inv = 1.0f / sL[rp + i];
        float4 o = o_acc[i];
        o.x *= inv; o.y *= inv; o.z *= inv; o.w *= inv;
        *(float4*)(ctx + (size_t)(b * cS + q0 + rp + i) * cH + h * cDH + d4) = o;
    }
}

__device__ __forceinline__ float block_reduce_sum(float v, float* red) {
#pragma unroll
    for (int o = 32; o; o >>= 1) v += __shfl_xor(v, o);
    __syncthreads();
    if ((threadIdx.x & 63) == 0) red[threadIdx.x >> 6] = v;
    __syncthreads();
    return red[0] + red[1] + red[2] + red[3];
}

// ---------------------------------------------------------------------------
// LN1 + LN2 + router, fp32 (selection-exact). Writes attention_output into
// out (residual base for expert scatter-add), xl bf16, logits to out tail.
__global__ __launch_bounds__(256) void ln_router_kernel(
    const float* __restrict__ dense, const float* __restrict__ resid,
    const float* __restrict__ g1, const float* __restrict__ b1,
    const float* __restrict__ g2, const float* __restrict__ b2,
    const float* __restrict__ Wr, const float* __restrict__ br,
    float* __restrict__ out, bf16* __restrict__ xlb,
    float* __restrict__ out_logits, float* __restrict__ wgt,
    int* __restrict__ counts, int* __restrict__ lists) {
    __shared__ float red[4];
    __shared__ float lred[4][8];
    const int t = blockIdx.x, tid = threadIdx.x;
    const size_t base = (size_t)t * cH;
    float v[3], s = 0.f;
#pragma unroll
    for (int i = 0; i < 3; ++i) {
        v[i] = dense[base + tid + 256 * i] + resid[base + tid + 256 * i];
        s += v[i];
    }
    const float mean = block_reduce_sum(s, red) * (1.0f / cH);
    float vs = 0.f;
#pragma unroll
    for (int i = 0; i < 3; ++i) { float d = v[i] - mean; vs += d * d; }
    const float rstd = rsqrtf(block_reduce_sum(vs, red) * (1.0f / cH) + 1e-12f);
    float a[3], s2 = 0.f;
#pragma unroll
    for (int i = 0; i < 3; ++i) {
        a[i] = (v[i] - mean) * rstd * g1[tid + 256 * i] + b1[tid + 256 * i];
        out[base + tid + 256 * i] = a[i];
        s2 += a[i];
    }
    const float mean2 = block_reduce_sum(s2, red) * (1.0f / cH);
    float vs2 = 0.f;
#pragma unroll
    for (int i = 0; i < 3; ++i) { float d = a[i] - mean2; vs2 += d * d; }
    const float rstd2 = rsqrtf(block_reduce_sum(vs2, red) * (1.0f / cH) + 1e-12f);
    float xl[3];
#pragma unroll
    for (int i = 0; i < 3; ++i) {
        xl[i] = (a[i] - mean2) * rstd2 * g2[tid + 256 * i] + b2[tid + 256 * i];
        xlb[base + tid + 256 * i] = (bf16)xl[i];
    }
    float lg[cE] = {};
#pragma unroll
    for (int i = 0; i < 3; ++i) {
        const float* wr = Wr + (size_t)(tid + 256 * i) * cE;
#pragma unroll
        for (int e = 0; e < cE; ++e) lg[e] += xl[i] * wr[e];
    }
#pragma unroll
    for (int e = 0; e < cE; ++e)
#pragma unroll
        for (int o = 32; o; o >>= 1) lg[e] += __shfl_xor(lg[e], o);
    if ((tid & 63) == 0)
#pragma unroll
        for (int e = 0; e < cE; ++e) lred[tid >> 6][e] = lg[e];
    __syncthreads();
    if (tid == 0) {
        float logits[cE];
#pragma unroll
        for (int e = 0; e < cE; ++e) {
            logits[e] = lred[0][e] + lred[1][e] + lred[2][e] + lred[3][e] + br[e];
            out_logits[(size_t)t * cE + e] = logits[e];
        }
        int i0 = 0;
        for (int e = 1; e < cE; ++e) if (logits[e] > logits[i0]) i0 = e;
        int i1 = (i0 == 0) ? 1 : 0;
        for (int e = 0; e < cE; ++e)
            if (e != i0 && logits[e] > logits[i1]) i1 = e;
        float e1 = __expf(logits[i1] - logits[i0]);
        float w0 = 1.0f / (1.0f + e1);
        float w1 = e1 * w0;
        wgt[t * 2 + 0] = w0;
        wgt[t * 2 + 1] = w1;
        int p0 = atomicAdd(&counts[i0], 1);
        lists[i0 * cT + p0] = t * 2 + 0;
        int p1 = atomicAdd(&counts[i1], 1);
        lists[i1 * cT + p1] = t * 2 + 1;
    }
}

// ---------------------------------------------------------------------------
// bf16 MFMA expert GEMMs (m97 recipe: 128x128 tile, BK=32, glds16 staging).
// ---------------------------------------------------------------------------
__global__ __launch_bounds__(256) void expert_up_mfma_kernel(
    const bf16* __restrict__ xlb,
    const bf16* __restrict__ WupT, const bf16* __restrict__ WnewT,
    const float* __restrict__ b_up, const float* __restrict__ b_new,
    const int* __restrict__ counts, const int* __restrict__ lists,
    bf16* __restrict__ act) {
    const int e = blockIdx.z;
    const int cnt = counts[e];
    const int m0 = blockIdx.y * 128;
    if (m0 >= cnt) return;
    const int n0 = blockIdx.x * 128;
    __shared__ short sA[128 * 32], sB1[128 * 32], sB2[128 * 32];
    __shared__ int rowa[128];
    const int t = threadIdx.x;
    if (t < 128) {
        int idx = m0 + t;
        rowa[t] = (idx < cnt) ? lists[e * cT + idx] : -1;
    }
    __syncthreads();
    const int lane = t & 63, w = t >> 6;
    const int wm = (w >> 1) * 64, wn = (w & 1) * 64;
    const int rA0 = t >> 2, kc8 = (t & 3) * 8;
    int a0 = rowa[rA0], a1 = rowa[rA0 + 64];
    const bf16* gA0 = xlb + (size_t)(a0 < 0 ? 0 : (a0 >> 1)) * cH + kc8;
    const bf16* gA1 = xlb + (size_t)(a1 < 0 ? 0 : (a1 >> 1)) * cH + kc8;
    const bf16* B1 = WupT + (size_t)e * cI * cH;
    const bf16* B2 = WnewT + (size_t)e * cI * cH;
    const bf16* gB10 = B1 + (size_t)(n0 + rA0) * cH + kc8;
    const bf16* gB11 = B1 + (size_t)(n0 + rA0 + 64) * cH + kc8;
    const bf16* gB20 = B2 + (size_t)(n0 + rA0) * cH + kc8;
    const bf16* gB21 = B2 + (size_t)(n0 + rA0 + 64) * cH + kc8;
    short* dA0  = sA  + t * 8;      short* dA1  = sA  + (t + 256) * 8;
    short* dB10 = sB1 + t * 8;      short* dB11 = sB1 + (t + 256) * 8;
    short* dB20 = sB2 + t * 8;      short* dB21 = sB2 + (t + 256) * 8;
    f4v zero = {0.f, 0.f, 0.f, 0.f};
    f4v acc1[4][4], acc2[4][4];
#pragma unroll
    for (int i = 0; i < 4; ++i)
#pragma unroll
        for (int j = 0; j < 4; ++j) { acc1[i][j] = zero; acc2[i][j] = zero; }
    const int fr = lane & 15, kg = (lane >> 4) * 8;
    for (int kk = 0; kk < cH; kk += 32) {
        glds16(gA0, dA0);   glds16(gA1, dA1);
        glds16(gB10, dB10); glds16(gB11, dB11);
        glds16(gB20, dB20); glds16(gB21, dB21);
        __syncthreads();
        s8v af[4], bf1[4], bf2[4];
#pragma unroll
        for (int i = 0; i < 4; ++i) {
            af[i]  = *(const s8v*)(sA  + (wm + i * 16 + fr) * 32 + kg);
            bf1[i] = *(const s8v*)(sB1 + (wn + i * 16 + fr) * 32 + kg);
            bf2[i] = *(const s8v*)(sB2 + (wn + i * 16 + fr) * 32 + kg);
        }
#pragma unroll
        for (int mi = 0; mi < 4; ++mi)
#pragma unroll
            for (int ni = 0; ni < 4; ++ni) {
                acc1[mi][ni] = __builtin_amdgcn_mfma_f32_16x16x32_bf16(
                    af[mi], bf1[ni], acc1[mi][ni], 0, 0, 0);
                acc2[mi][ni] = __builtin_amdgcn_mfma_f32_16x16x32_bf16(
                    af[mi], bf2[ni], acc2[mi][ni], 0, 0, 0);
            }
        __syncthreads();
        gA0 += 32; gA1 += 32; gB10 += 32; gB11 += 32; gB20 += 32; gB21 += 32;
    }
    const int cn = lane & 15, rq = (lane >> 4) * 4;
#pragma unroll
    for (int mi = 0; mi < 4; ++mi)
#pragma unroll
        for (int r = 0; r < 4; ++r) {
            int ml = wm + mi * 16 + rq + r;
            int a = rowa[ml];
            if (a < 0) continue;
            bf16* orow = act + (size_t)a * cI + n0 + wn;
#pragma unroll
            for (int ni = 0; ni < 4; ++ni) {
                int nl = ni * 16 + cn;
                float up = acc1[mi][ni][r] + b_up[e * cI + n0 + wn + nl];
                float nw = acc2[mi][ni][r] + b_new[e * cI + n0 + wn + nl];
                float g = 0.5f * up * (1.0f + erff(up * 0.70710678118654752f));
                orow[nl] = (bf16)(g * nw);
            }
        }
}

__global__ __launch_bounds__(256) void expert_down_mfma_kernel(
    const bf16* __restrict__ act, const bf16* __restrict__ WdownT,
    const float* __restrict__ b_down,
    const int* __restrict__ counts, const int* __restrict__ lists,
    const float* __restrict__ wgt, float* __restrict__ out) {
    const int e = blockIdx.z;
    const int cnt = counts[e];
    const int m0 = blockIdx.y * 128;
    if (m0 >= cnt) return;
    const int n0 = blockIdx.x * 128;
    __shared__ short sA[128 * 32], sB[128 * 32];
    __shared__ int rowa[128];
    const int t = threadIdx.x;
    if (t < 128) {
        int idx = m0 + t;
        rowa[t] = (idx < cnt) ? lists[e * cT + idx] : -1;
    }
    __syncthreads();
    const int lane = t & 63, w = t >> 6;
    const int wm = (w >> 1) * 64, wn = (w & 1) * 64;
    const int rA0 = t >> 2, kc8 = (t & 3) * 8;
    int a0 = rowa[rA0], a1 = rowa[rA0 + 64];
    const bf16* gA0 = act + (size_t)(a0 < 0 ? 0 : a0) * cI + kc8;
    const bf16* gA1 = act + (size_t)(a1 < 0 ? 0 : a1) * cI + kc8;
    const bf16* BT = WdownT + (size_t)e * cH * cI;
    const bf16* gB0 = BT + (size_t)(n0 + rA0) * cI + kc8;
    const bf16* gB1 = BT + (size_t)(n0 + rA0 + 64) * cI + kc8;
    short* dA0 = sA + t * 8;       short* dA1 = sA + (t + 256) * 8;
    short* dB0 = sB + t * 8;       short* dB1 = sB + (t + 256) * 8;
    f4v zero = {0.f, 0.f, 0.f, 0.f};
    f4v acc[4][4];
#pragma unroll
    for (int i = 0; i < 4; ++i)
#pragma unroll
        for (int j = 0; j < 4; ++j) acc[i][j] = zero;
    const int fr = lane & 15, kg = (lane >> 4) * 8;
    for (int kk = 0; kk < cI; kk += 32) {
        glds16(gA0, dA0); glds16(gA1, dA1);
        glds16(gB0, dB0); glds16(gB1, dB1);
        __syncthreads();
        s8v af[4], bf[4];
#pragma unroll
        for (int i = 0; i < 4; ++i) af[i] = *(const s8v*)(sA + (wm + i * 16 + fr) * 32 + kg);
#pragma unroll
        for (int i = 0; i < 4; ++i) bf[i] = *(const s8v*)(sB + (wn + i * 16 + fr) * 32 + kg);
#pragma unroll
        for (int mi = 0; mi < 4; ++mi)
#pragma unroll
            for (int ni = 0; ni < 4; ++ni)
                acc[mi][ni] = __builtin_amdgcn_mfma_f32_16x16x32_bf16(
                    af[mi], bf[ni], acc[mi][ni], 0, 0, 0);
        __syncthreads();
        gA0 += 32; gA1 += 32; gB0 += 32; gB1 += 32;
    }
    const int cn = lane & 15, rq = (lane >> 4) * 4;
#pragma unroll
    for (int mi = 0; mi < 4; ++mi)
#pragma unroll
        for (int r = 0; r < 4; ++r) {
            int ml = wm + mi * 16 + rq + r;
            int a = rowa[ml];
            if (a < 0) continue;
            int token = a >> 1;
            float wv = wgt[a];
#pragma unroll
            for (int ni = 0; ni < 4; ++ni) {
                int n = n0 + wn + ni * 16 + cn;
                atomicAdd(&out[(size_t)token * cH + n],
                          wv * (acc[mi][ni][r] + b_down[e * cH + n]));
            }
        }
}

// ---------------------------------------------------------------------------
extern "C" void kernel_launch(void* const* d_in, const int* in_sizes, int n_in,
                              void* d_out, int out_size, void* d_ws, size_t ws_size,
                              hipStream_t stream) {
    const float* x      = (const float*)d_in[0];
    const float* Wq     = (const float*)d_in[1];
    const float* bq     = (const float*)d_in[2];
    const float* Wk     = (const float*)d_in[3];
    const float* bk     = (const float*)d_in[4];
    const float* Wv     = (const float*)d_in[5];
    const float* bv     = (const float*)d_in[6];
    const float* Wo     = (const float*)d_in[7];
    const float* bo     = (const float*)d_in[8];
    const float* ln1g   = (const float*)d_in[9];
    const float* ln1b   = (const float*)d_in[10];
    const float* ln2g   = (const float*)d_in[11];
    const float* ln2b   = (const float*)d_in[12];
    const float* Wr     = (const float*)d_in[13];
    const float* br     = (const float*)d_in[14];
    const float* W_up   = (const float*)d_in[15];
    const float* b_up   = (const float*)d_in[16];
    const float* W_new  = (const float*)d_in[17];
    const float* b_new  = (const float*)d_in[18];
    const float* W_down = (const float*)d_in[19];
    const float* b_down = (const float*)d_in[20];

    float* out = (float*)d_out;
    float* ws  = (float*)d_ws;

    bf16* WupT   = (bf16*)(ws + OFF_WUP_T);
    bf16* WnewT  = (bf16*)(ws + OFF_WNEW_T);
    bf16* WdownT = (bf16*)(ws + OFF_WDOWN_T);
    float* q     = ws + OFF_QKV;
    float* k     = ws + OFF_QKV + TH;
    float* v     = ws + OFF_QKV + 2 * TH;
    float* tmp   = ws + OFF_QKV + 3 * TH;
    bf16* act    = (bf16*)(ws + OFF_QKV);   // aliases q/k/v/tmp (dead by then)
    float* ctx   = ws + OFF_CTX;
    bf16* xlb    = (bf16*)(ws + OFF_XLB);
    float* wgt   = ws + OFF_WGT;
    int* counts  = (int*)(ws + OFF_COUNTS);
    int* lists   = (int*)(ws + OFF_LISTS);

    init_counts_kernel<<<1, 64, 0, stream>>>(counts);

    // expert weight transpose+convert
    transpose_bf16_kernel<<<dim3(48, 12, cE), 256, 0, stream>>>(W_up, WupT, cH, cI);
    transpose_bf16_kernel<<<dim3(48, 12, cE), 256, 0, stream>>>(W_new, WnewT, cH, cI);
    transpose_bf16_kernel<<<dim3(12, 48, cE), 256, 0, stream>>>(W_down, WdownT, cI, cH);

    // fp32 pre-router path (selection-exact)
    gemm_qkv_kernel<<<dim3(cH / 64, cT / 64, 3), 256, 0, stream>>>(
        x, Wq, Wk, Wv, bq, bk, bv, q, k, v);
    attn_kernel<<<dim3(cS / 64, cNH, cB), 256, 0, stream>>>(q, k, v, ctx);
    gemm_bias_kernel<<<dim3(cH / 64, cT / 64), 256, 0, stream>>>(ctx, Wo, bo, tmp, cT, cH, cH);
    ln_router_kernel<<<cT, 256, 0, stream>>>(
        tmp, x, ln1g, ln1b, ln2g, ln2b, Wr, br,
        out, xlb, out + TH, wgt, counts, lists);

    // bf16 MFMA experts (scatter-add into out)
    expert_up_mfma_kernel<<<dim3(cI / 128, cT / 128, cE), 256, 0, stream>>>(
        xlb, WupT, WnewT, b_up, b_new, counts, lists, act);
    expert_down_mfma_kernel<<<dim3(cH / 128, cT / 128, cE), 256, 0, stream>>>(
        act, WdownT, b_down, counts, lists, wgt, out);
}

// Round 5
// 1092.782 us; speedup vs baseline: 2.4256x; 1.1025x over previous
//
#include <hip/hip_runtime.h>
#include <hip/hip_bf16.h>
#include <cmath>

// ---------------------------------------------------------------------------
// BertLayer + top-2 MoE, MI355X. Round 5:
//  - expert_up re-tiled 128x64 (64 AGPR dual-acc -> 2-3 waves/SIMD, was 1)
//  - fp32 projections re-tiled 128x128, 8x8/thread, B staged via glds16
//  - everything else carried from round 4 (proven).
// ---------------------------------------------------------------------------

constexpr int cB = 8, cS = 512, cH = 768, cNH = 12, cDH = 64, cI = 3072, cE = 8;
constexpr int cT = cB * cS;                       // 4096 tokens
constexpr size_t TH = (size_t)cT * cH;            // 3,145,728

typedef __hip_bfloat16 bf16;
typedef __attribute__((ext_vector_type(8))) short s8v;   // 8 bf16 = 4 VGPRs
typedef __attribute__((ext_vector_type(4))) float f4v;   // MFMA accumulator

// ---- workspace layout (float units) ---------------------------------------
constexpr size_t SZ_WEXP     = (size_t)cE * cI * cH / 2;        // 9,437,184
constexpr size_t OFF_WUP_T   = 0;                               // [E][I][H] bf16
constexpr size_t OFF_WNEW_T  = OFF_WUP_T + SZ_WEXP;
constexpr size_t OFF_WDOWN_T = OFF_WNEW_T + SZ_WEXP;            // [E][H][I] bf16
constexpr size_t OFF_QKV     = OFF_WDOWN_T + SZ_WEXP;           // q,k,v,tmp fp32
constexpr size_t OFF_CTX     = OFF_QKV + 4 * TH;                // ctx fp32
constexpr size_t OFF_XLB     = OFF_CTX + TH;                    // xl bf16
constexpr size_t OFF_WGT     = OFF_XLB + TH / 2;                // 2T fp32
constexpr size_t OFF_COUNTS  = OFF_WGT + 2 * cT;                // int[16]
constexpr size_t OFF_LISTS   = OFF_COUNTS + 16;                 // int[E*T]
// act (bf16) aliases q/k/v/tmp region (dead once ln_router consumed tmp).

// ---------------------------------------------------------------------------
__device__ __forceinline__ void glds16(const void* g, void* l) {
    __builtin_amdgcn_global_load_lds(
        (const __attribute__((address_space(1))) unsigned int*)g,
        (__attribute__((address_space(3))) unsigned int*)l, 16, 0, 0);
}

__global__ void init_counts_kernel(int* __restrict__ counts) {
    if (threadIdx.x < cE) counts[threadIdx.x] = 0;
}

// src [z][R][C] fp32 -> dst [z][C][R] bf16   (R,C multiples of 64)
__global__ __launch_bounds__(256) void transpose_bf16_kernel(
    const float* __restrict__ src, bf16* __restrict__ dst, int R, int C) {
    __shared__ float tile[64][65];
    const size_t zb = (size_t)blockIdx.z * R * C;
    const int r0 = blockIdx.y * 64, c0 = blockIdx.x * 64;
    const int t = threadIdx.x;
    const int lr = t >> 4, lc = (t & 15) * 4;
#pragma unroll
    for (int i = 0; i < 4; ++i) {
        float4 v = *(const float4*)(src + zb + (size_t)(r0 + lr + i * 16) * C + c0 + lc);
        tile[lr + i * 16][lc + 0] = v.x; tile[lr + i * 16][lc + 1] = v.y;
        tile[lr + i * 16][lc + 2] = v.z; tile[lr + i * 16][lc + 3] = v.w;
    }
    __syncthreads();
#pragma unroll
    for (int i = 0; i < 4; ++i) {
        int cr = lr + i * 16;
        bf16 o[4];
#pragma unroll
        for (int j = 0; j < 4; ++j) o[j] = (bf16)tile[lc + j][cr];
        *(uint2*)(dst + zb + (size_t)(c0 + cr) * R + r0 + lc) = *(uint2*)o;
    }
}

// ---------------------------------------------------------------------------
// fp32 tile GEMM, 128x128 tile, BK=16, 8x8 per thread. B staged via glds16.
__device__ __forceinline__ void gemm_body128(
    const float* __restrict__ A, const float* __restrict__ B,
    const float* __restrict__ bias, float* __restrict__ C,
    int N, int K, int m0, int n0) {
    __shared__ float As[16 * 132];   // [k][m], stride 132 (bank-spread)
    __shared__ float Bs[16 * 128];   // [k][n], contiguous (glds16 target)
    const int t = threadIdx.x;
    const int tx = t & 15, ty = t >> 4;        // n-group, m-group
    const int ar = t >> 2, ac = (t & 3) * 4;   // A loader: rows ar, ar+64
    const int bc = (t & 31) * 4, br = t >> 5;  // B loader: rows br, br+8
    const float* gB0 = B + (size_t)br * N + n0 + bc;
    float* dB0 = Bs + t * 4;
    float acc[8][8] = {};
    for (int k0 = 0; k0 < K; k0 += 16) {
        float4 a0 = *(const float4*)(A + (size_t)(m0 + ar) * K + k0 + ac);
        float4 a1 = *(const float4*)(A + (size_t)(m0 + ar + 64) * K + k0 + ac);
        glds16(gB0, dB0);
        glds16(gB0 + (size_t)8 * N, dB0 + 1024);
        As[(ac + 0) * 132 + ar] = a0.x; As[(ac + 1) * 132 + ar] = a0.y;
        As[(ac + 2) * 132 + ar] = a0.z; As[(ac + 3) * 132 + ar] = a0.w;
        As[(ac + 0) * 132 + ar + 64] = a1.x; As[(ac + 1) * 132 + ar + 64] = a1.y;
        As[(ac + 2) * 132 + ar + 64] = a1.z; As[(ac + 3) * 132 + ar + 64] = a1.w;
        __syncthreads();
#pragma unroll
        for (int kk = 0; kk < 16; ++kk) {
            float a[8], b[8];
            *(float4*)&a[0] = *(const float4*)&As[kk * 132 + ty * 8];
            *(float4*)&a[4] = *(const float4*)&As[kk * 132 + ty * 8 + 4];
            *(float4*)&b[0] = *(const float4*)&Bs[kk * 128 + tx * 4];
            *(float4*)&b[4] = *(const float4*)&Bs[kk * 128 + tx * 4 + 64];
#pragma unroll
            for (int i = 0; i < 8; ++i)
#pragma unroll
                for (int j = 0; j < 8; ++j) acc[i][j] += a[i] * b[j];
        }
        __syncthreads();
        gB0 += (size_t)16 * N;
    }
#pragma unroll
    for (int i = 0; i < 8; ++i) {
        int m = m0 + ty * 8 + i;
        float4 o0, o1;
        o0.x = acc[i][0] + bias[n0 + tx * 4 + 0];
        o0.y = acc[i][1] + bias[n0 + tx * 4 + 1];
        o0.z = acc[i][2] + bias[n0 + tx * 4 + 2];
        o0.w = acc[i][3] + bias[n0 + tx * 4 + 3];
        o1.x = acc[i][4] + bias[n0 + 64 + tx * 4 + 0];
        o1.y = acc[i][5] + bias[n0 + 64 + tx * 4 + 1];
        o1.z = acc[i][6] + bias[n0 + 64 + tx * 4 + 2];
        o1.w = acc[i][7] + bias[n0 + 64 + tx * 4 + 3];
        *(float4*)(C + (size_t)m * N + n0 + tx * 4) = o0;
        *(float4*)(C + (size_t)m * N + n0 + 64 + tx * 4) = o1;
    }
}

// QKV: one launch, grid.z selects W/bias/output (shared A stays hot in L2).
__global__ __launch_bounds__(256) void gemm_qkv_kernel(
    const float* __restrict__ A,
    const float* __restrict__ Wq, const float* __restrict__ Wk,
    const float* __restrict__ Wv,
    const float* __restrict__ bq, const float* __restrict__ bk,
    const float* __restrict__ bv,
    float* __restrict__ q, float* __restrict__ k, float* __restrict__ v) {
    const int z = blockIdx.z;
    const float* B = (z == 0) ? Wq : (z == 1) ? Wk : Wv;
    const float* bias = (z == 0) ? bq : (z == 1) ? bk : bv;
    float* C = (z == 0) ? q : (z == 1) ? k : v;
    gemm_body128(A, B, bias, C, cH, cH, blockIdx.y * 128, blockIdx.x * 128);
}

__global__ __launch_bounds__(256) void gemm_bias_kernel(
    const float* __restrict__ A, const float* __restrict__ B,
    const float* __restrict__ bias, float* __restrict__ C,
    int M, int N, int K) {
    gemm_body128(A, B, bias, C, N, K, blockIdx.y * 128, blockIdx.x * 128);
}

// ---------------------------------------------------------------------------
// Flash-style fp32 attention (round-4 proven). Block = 64 q-rows x head x batch.
__global__ __launch_bounds__(256) void attn_kernel(
    const float* __restrict__ q, const float* __restrict__ k,
    const float* __restrict__ v, float* __restrict__ ctx) {
    __shared__ float sQ[64][68];
    __shared__ float sKV[64][68];
    __shared__ float sS[64][68];
    __shared__ float sM[64], sL[64], sAl[64];
    const int q0 = blockIdx.x * 64, h = blockIdx.y, b = blockIdx.z;
    const int t = threadIdx.x;
    const int lr = t >> 2, lq = (t & 3) * 16;
    {
        const float* gq = q + (size_t)(b * cS + q0 + lr) * cH + h * cDH + lq;
#pragma unroll
        for (int j = 0; j < 4; ++j) {
            float4 x = *(const float4*)(gq + j * 4);
            x.x *= 0.125f; x.y *= 0.125f; x.z *= 0.125f; x.w *= 0.125f;
            *(float4*)&sQ[lr][lq + j * 4] = x;
        }
    }
    if (t < 64) { sM[t] = -1e30f; sL[t] = 0.f; }
    const int c0 = t & 15, rr = (t >> 4) * 4;
    const int d4 = (t & 15) * 4, rp = (t >> 4) * 4;
    const int sr = t >> 2, sc = (t & 3) * 16;
    float4 o_acc[4];
#pragma unroll
    for (int i = 0; i < 4; ++i) o_acc[i] = make_float4(0.f, 0.f, 0.f, 0.f);

    for (int kt = 0; kt < 8; ++kt) {
        float4 kreg[4];
        {
            const float* gk = k + (size_t)(b * cS + kt * 64 + lr) * cH + h * cDH + lq;
#pragma unroll
            for (int j = 0; j < 4; ++j) kreg[j] = *(const float4*)(gk + j * 4);
        }
        __syncthreads();
#pragma unroll
        for (int j = 0; j < 4; ++j) *(float4*)&sKV[lr][lq + j * 4] = kreg[j];
        __syncthreads();
        float accS[4][4] = {};
#pragma unroll
        for (int d = 0; d < 64; d += 4) {
            float4 qv[4], kv[4];
#pragma unroll
            for (int i = 0; i < 4; ++i) qv[i] = *(const float4*)&sQ[rr + i][d];
#pragma unroll
            for (int j = 0; j < 4; ++j) kv[j] = *(const float4*)&sKV[c0 + 16 * j][d];
#pragma unroll
            for (int i = 0; i < 4; ++i)
#pragma unroll
                for (int j = 0; j < 4; ++j)
                    accS[i][j] += qv[i].x * kv[j].x + qv[i].y * kv[j].y +
                                  qv[i].z * kv[j].z + qv[i].w * kv[j].w;
        }
#pragma unroll
        for (int i = 0; i < 4; ++i)
#pragma unroll
            for (int j = 0; j < 4; ++j) sS[rr + i][c0 + 16 * j] = accS[i][j];
        float4 vreg[4];
        {
            const float* gv = v + (size_t)(b * cS + kt * 64 + lr) * cH + h * cDH + lq;
#pragma unroll
            for (int j = 0; j < 4; ++j) vreg[j] = *(const float4*)(gv + j * 4);
        }
        __syncthreads();
        {
            float4 s[4];
#pragma unroll
            for (int j = 0; j < 4; ++j) s[j] = *(const float4*)&sS[sr][sc + j * 4];
            float m = -1e30f;
#pragma unroll
            for (int j = 0; j < 4; ++j)
                m = fmaxf(m, fmaxf(fmaxf(s[j].x, s[j].y), fmaxf(s[j].z, s[j].w)));
            m = fmaxf(m, __shfl_xor(m, 1));
            m = fmaxf(m, __shfl_xor(m, 2));
            float m_old = sM[sr];
            float m_new = fmaxf(m_old, m);
            float sum = 0.f;
#pragma unroll
            for (int j = 0; j < 4; ++j) {
                s[j].x = __expf(s[j].x - m_new); s[j].y = __expf(s[j].y - m_new);
                s[j].z = __expf(s[j].z - m_new); s[j].w = __expf(s[j].w - m_new);
                sum += s[j].x + s[j].y + s[j].z + s[j].w;
                *(float4*)&sS[sr][sc + j * 4] = s[j];
            }
            sum += __shfl_xor(sum, 1);
            sum += __shfl_xor(sum, 2);
            if ((t & 3) == 0) {
                float alpha = __expf(m_old - m_new);
                sAl[sr] = alpha;
                sM[sr] = m_new;
                sL[sr] = sL[sr] * alpha + sum;
            }
        }
#pragma unroll
        for (int j = 0; j < 4; ++j) *(float4*)&sKV[lr][lq + j * 4] = vreg[j];
        __syncthreads();
#pragma unroll
        for (int i = 0; i < 4; ++i) {
            float al = sAl[rp + i];
            o_acc[i].x *= al; o_acc[i].y *= al; o_acc[i].z *= al; o_acc[i].w *= al;
        }
        for (int kk4 = 0; kk4 < 64; kk4 += 4) {
            float4 pv[4], vv[4];
#pragma unroll
            for (int i = 0; i < 4; ++i) pv[i] = *(const float4*)&sS[rp + i][kk4];
#pragma unroll
            for (int j = 0; j < 4; ++j) vv[j] = *(const float4*)&sKV[kk4 + j][d4];
#pragma unroll
            for (int i = 0; i < 4; ++i) {
                o_acc[i].x += pv[i].x * vv[0].x + pv[i].y * vv[1].x +
                              pv[i].z * vv[2].x + pv[i].w * vv[3].x;
                o_acc[i].y += pv[i].x * vv[0].y + pv[i].y * vv[1].y +
                              pv[i].z * vv[2].y + pv[i].w * vv[3].y;
                o_acc[i].z += pv[i].x * vv[0].z + pv[i].y * vv[1].z +
                              pv[i].z * vv[2].z + pv[i].w * vv[3].z;
                o_acc[i].w += pv[i].x * vv[0].w + pv[i].y * vv[1].w +
                              pv[i].z * vv[2].w + pv[i].w * vv[3].w;
            }
        }
    }
    __syncthreads();
#pragma unroll
    for (int i = 0; i < 4; ++i) {
        float inv = 1.0f / sL[rp + i];
        float4 o = o_acc[i];
        o.x *= inv; o.y *= inv; o.z *= inv; o.w *= inv;
        *(float4*)(ctx + (size_t)(b * cS + q0 + rp + i) * cH + h * cDH + d4) = o;
    }
}

__device__ __forceinline__ float block_reduce_sum(float v, float* red) {
#pragma unroll
    for (int o = 32; o; o >>= 1) v += __shfl_xor(v, o);
    __syncthreads();
    if ((threadIdx.x & 63) == 0) red[threadIdx.x >> 6] = v;
    __syncthreads();
    return red[0] + red[1] + red[2] + red[3];
}

// ---------------------------------------------------------------------------
// LN1 + LN2 + router, fp32 (selection-exact, round-3 proven).
__global__ __launch_bounds__(256) void ln_router_kernel(
    const float* __restrict__ dense, const float* __restrict__ resid,
    const float* __restrict__ g1, const float* __restrict__ b1,
    const float* __restrict__ g2, const float* __restrict__ b2,
    const float* __restrict__ Wr, const float* __restrict__ br,
    float* __restrict__ out, bf16* __restrict__ xlb,
    float* __restrict__ out_logits, float* __restrict__ wgt,
    int* __restrict__ counts, int* __restrict__ lists) {
    __shared__ float red[4];
    __shared__ float lred[4][8];
    const int t = blockIdx.x, tid = threadIdx.x;
    const size_t base = (size_t)t * cH;
    float v[3], s = 0.f;
#pragma unroll
    for (int i = 0; i < 3; ++i) {
        v[i] = dense[base + tid + 256 * i] + resid[base + tid + 256 * i];
        s += v[i];
    }
    const float mean = block_reduce_sum(s, red) * (1.0f / cH);
    float vs = 0.f;
#pragma unroll
    for (int i = 0; i < 3; ++i) { float d = v[i] - mean; vs += d * d; }
    const float rstd = rsqrtf(block_reduce_sum(vs, red) * (1.0f / cH) + 1e-12f);
    float a[3], s2 = 0.f;
#pragma unroll
    for (int i = 0; i < 3; ++i) {
        a[i] = (v[i] - mean) * rstd * g1[tid + 256 * i] + b1[tid + 256 * i];
        out[base + tid + 256 * i] = a[i];
        s2 += a[i];
    }
    const float mean2 = block_reduce_sum(s2, red) * (1.0f / cH);
    float vs2 = 0.f;
#pragma unroll
    for (int i = 0; i < 3; ++i) { float d = a[i] - mean2; vs2 += d * d; }
    const float rstd2 = rsqrtf(block_reduce_sum(vs2, red) * (1.0f / cH) + 1e-12f);
    float xl[3];
#pragma unroll
    for (int i = 0; i < 3; ++i) {
        xl[i] = (a[i] - mean2) * rstd2 * g2[tid + 256 * i] + b2[tid + 256 * i];
        xlb[base + tid + 256 * i] = (bf16)xl[i];
    }
    float lg[cE] = {};
#pragma unroll
    for (int i = 0; i < 3; ++i) {
        const float* wr = Wr + (size_t)(tid + 256 * i) * cE;
#pragma unroll
        for (int e = 0; e < cE; ++e) lg[e] += xl[i] * wr[e];
    }
#pragma unroll
    for (int e = 0; e < cE; ++e)
#pragma unroll
        for (int o = 32; o; o >>= 1) lg[e] += __shfl_xor(lg[e], o);
    if ((tid & 63) == 0)
#pragma unroll
        for (int e = 0; e < cE; ++e) lred[tid >> 6][e] = lg[e];
    __syncthreads();
    if (tid == 0) {
        float logits[cE];
#pragma unroll
        for (int e = 0; e < cE; ++e) {
            logits[e] = lred[0][e] + lred[1][e] + lred[2][e] + lred[3][e] + br[e];
            out_logits[(size_t)t * cE + e] = logits[e];
        }
        int i0 = 0;
        for (int e = 1; e < cE; ++e) if (logits[e] > logits[i0]) i0 = e;
        int i1 = (i0 == 0) ? 1 : 0;
        for (int e = 0; e < cE; ++e)
            if (e != i0 && logits[e] > logits[i1]) i1 = e;
        float e1 = __expf(logits[i1] - logits[i0]);
        float w0 = 1.0f / (1.0f + e1);
        float w1 = e1 * w0;
        wgt[t * 2 + 0] = w0;
        wgt[t * 2 + 1] = w1;
        int p0 = atomicAdd(&counts[i0], 1);
        lists[i0 * cT + p0] = t * 2 + 0;
        int p1 = atomicAdd(&counts[i1], 1);
        lists[i1 * cT + p1] = t * 2 + 1;
    }
}

// ---------------------------------------------------------------------------
// Expert up, 128x64 tile: per-wave 64x32 dual-acc (64 AGPR total).
__global__ __launch_bounds__(256) void expert_up_mfma_kernel(
    const bf16* __restrict__ xlb,
    const bf16* __restrict__ WupT, const bf16* __restrict__ WnewT,
    const float* __restrict__ b_up, const float* __restrict__ b_new,
    const int* __restrict__ counts, const int* __restrict__ lists,
    bf16* __restrict__ act) {
    const int e = blockIdx.z;
    const int cnt = counts[e];
    const int m0 = blockIdx.y * 128;
    if (m0 >= cnt) return;
    const int n0 = blockIdx.x * 64;
    __shared__ short sA[128 * 32], sB1[64 * 32], sB2[64 * 32];
    __shared__ int rowa[128];
    const int t = threadIdx.x;
    if (t < 128) {
        int idx = m0 + t;
        rowa[t] = (idx < cnt) ? lists[e * cT + idx] : -1;
    }
    __syncthreads();
    const int lane = t & 63, w = t >> 6;
    const int wm = (w >> 1) * 64, wn = (w & 1) * 32;
    const int rA0 = t >> 2, kc8 = (t & 3) * 8;
    int a0 = rowa[rA0], a1 = rowa[rA0 + 64];
    const bf16* gA0 = xlb + (size_t)(a0 < 0 ? 0 : (a0 >> 1)) * cH + kc8;
    const bf16* gA1 = xlb + (size_t)(a1 < 0 ? 0 : (a1 >> 1)) * cH + kc8;
    const bf16* B1 = WupT + (size_t)e * cI * cH;
    const bf16* B2 = WnewT + (size_t)e * cI * cH;
    const bf16* gB1 = B1 + (size_t)(n0 + rA0) * cH + kc8;
    const bf16* gB2 = B2 + (size_t)(n0 + rA0) * cH + kc8;
    short* dA0 = sA + t * 8;   short* dA1 = sA + (t + 256) * 8;
    short* dB1 = sB1 + t * 8;  short* dB2 = sB2 + t * 8;
    f4v zero = {0.f, 0.f, 0.f, 0.f};
    f4v acc1[4][2], acc2[4][2];
#pragma unroll
    for (int i = 0; i < 4; ++i)
#pragma unroll
        for (int j = 0; j < 2; ++j) { acc1[i][j] = zero; acc2[i][j] = zero; }
    const int fr = lane & 15, kg = (lane >> 4) * 8;
    for (int kk = 0; kk < cH; kk += 32) {
        glds16(gA0, dA0); glds16(gA1, dA1);
        glds16(gB1, dB1); glds16(gB2, dB2);
        __syncthreads();
        s8v af[4], bf1[2], bf2[2];
#pragma unroll
        for (int i = 0; i < 4; ++i)
            af[i] = *(const s8v*)(sA + (wm + i * 16 + fr) * 32 + kg);
#pragma unroll
        for (int j = 0; j < 2; ++j) {
            bf1[j] = *(const s8v*)(sB1 + (wn + j * 16 + fr) * 32 + kg);
            bf2[j] = *(const s8v*)(sB2 + (wn + j * 16 + fr) * 32 + kg);
        }
#pragma unroll
        for (int mi = 0; mi < 4; ++mi)
#pragma unroll
            for (int ni = 0; ni < 2; ++ni) {
                acc1[mi][ni] = __builtin_amdgcn_mfma_f32_16x16x32_bf16(
                    af[mi], bf1[ni], acc1[mi][ni], 0, 0, 0);
                acc2[mi][ni] = __builtin_amdgcn_mfma_f32_16x16x32_bf16(
                    af[mi], bf2[ni], acc2[mi][ni], 0, 0, 0);
            }
        __syncthreads();
        gA0 += 32; gA1 += 32; gB1 += 32; gB2 += 32;
    }
    const int cn = lane & 15, rq = (lane >> 4) * 4;
#pragma unroll
    for (int mi = 0; mi < 4; ++mi)
#pragma unroll
        for (int r = 0; r < 4; ++r) {
            int ml = wm + mi * 16 + rq + r;
            int a = rowa[ml];
            if (a < 0) continue;
            bf16* orow = act + (size_t)a * cI + n0 + wn;
#pragma unroll
            for (int ni = 0; ni < 2; ++ni) {
                int nl = ni * 16 + cn;
                float up = acc1[mi][ni][r] + b_up[e * cI + n0 + wn + nl];
                float nw = acc2[mi][ni][r] + b_new[e * cI + n0 + wn + nl];
                float g = 0.5f * up * (1.0f + erff(up * 0.70710678118654752f));
                orow[nl] = (bf16)(g * nw);
            }
        }
}

// Expert down (round-3 proven, 128x128, 64 AGPR): out += w*(act@WdownT+b).
__global__ __launch_bounds__(256) void expert_down_mfma_kernel(
    const bf16* __restrict__ act, const bf16* __restrict__ WdownT,
    const float* __restrict__ b_down,
    const int* __restrict__ counts, const int* __restrict__ lists,
    const float* __restrict__ wgt, float* __restrict__ out) {
    const int e = blockIdx.z;
    const int cnt = counts[e];
    const int m0 = blockIdx.y * 128;
    if (m0 >= cnt) return;
    const int n0 = blockIdx.x * 128;
    __shared__ short sA[128 * 32], sB[128 * 32];
    __shared__ int rowa[128];
    const int t = threadIdx.x;
    if (t < 128) {
        int idx = m0 + t;
        rowa[t] = (idx < cnt) ? lists[e * cT + idx] : -1;
    }
    __syncthreads();
    const int lane = t & 63, w = t >> 6;
    const int wm = (w >> 1) * 64, wn = (w & 1) * 64;
    const int rA0 = t >> 2, kc8 = (t & 3) * 8;
    int a0 = rowa[rA0], a1 = rowa[rA0 + 64];
    const bf16* gA0 = act + (size_t)(a0 < 0 ? 0 : a0) * cI + kc8;
    const bf16* gA1 = act + (size_t)(a1 < 0 ? 0 : a1) * cI + kc8;
    const bf16* BT = WdownT + (size_t)e * cH * cI;
    const bf16* gB0 = BT + (size_t)(n0 + rA0) * cI + kc8;
    const bf16* gB1 = BT + (size_t)(n0 + rA0 + 64) * cI + kc8;
    short* dA0 = sA + t * 8;       short* dA1 = sA + (t + 256) * 8;
    short* dB0 = sB + t * 8;       short* dB1 = sB + (t + 256) * 8;
    f4v zero = {0.f, 0.f, 0.f, 0.f};
    f4v acc[4][4];
#pragma unroll
    for (int i = 0; i < 4; ++i)
#pragma unroll
        for (int j = 0; j < 4; ++j) acc[i][j] = zero;
    const int fr = lane & 15, kg = (lane >> 4) * 8;
    for (int kk = 0; kk < cI; kk += 32) {
        glds16(gA0, dA0); glds16(gA1, dA1);
        glds16(gB0, dB0); glds16(gB1, dB1);
        __syncthreads();
        s8v af[4], bf[4];
#pragma unroll
        for (int i = 0; i < 4; ++i) af[i] = *(const s8v*)(sA + (wm + i * 16 + fr) * 32 + kg);
#pragma unroll
        for (int i = 0; i < 4; ++i) bf[i] = *(const s8v*)(sB + (wn + i * 16 + fr) * 32 + kg);
#pragma unroll
        for (int mi = 0; mi < 4; ++mi)
#pragma unroll
            for (int ni = 0; ni < 4; ++ni)
                acc[mi][ni] = __builtin_amdgcn_mfma_f32_16x16x32_bf16(
                    af[mi], bf[ni], acc[mi][ni], 0, 0, 0);
        __syncthreads();
        gA0 += 32; gA1 += 32; gB0 += 32; gB1 += 32;
    }
    const int cn = lane & 15, rq = (lane >> 4) * 4;
#pragma unroll
    for (int mi = 0; mi < 4; ++mi)
#pragma unroll
        for (int r = 0; r < 4; ++r) {
            int ml = wm + mi * 16 + rq + r;
            int a = rowa[ml];
            if (a < 0) continue;
            int token = a >> 1;
            float wv = wgt[a];
#pragma unroll
            for (int ni = 0; ni < 4; ++ni) {
                int n = n0 + wn + ni * 16 + cn;
                atomicAdd(&out[(size_t)token * cH + n],
                          wv * (acc[mi][ni][r] + b_down[e * cH + n]));
            }
        }
}

// ---------------------------------------------------------------------------
extern "C" void kernel_launch(void* const* d_in, const int* in_sizes, int n_in,
                              void* d_out, int out_size, void* d_ws, size_t ws_size,
                              hipStream_t stream) {
    const float* x      = (const float*)d_in[0];
    const float* Wq     = (const float*)d_in[1];
    const float* bq     = (const float*)d_in[2];
    const float* Wk     = (const float*)d_in[3];
    const float* bk     = (const float*)d_in[4];
    const float* Wv     = (const float*)d_in[5];
    const float* bv     = (const float*)d_in[6];
    const float* Wo     = (const float*)d_in[7];
    const float* bo     = (const float*)d_in[8];
    const float* ln1g   = (const float*)d_in[9];
    const float* ln1b   = (const float*)d_in[10];
    const float* ln2g   = (const float*)d_in[11];
    const float* ln2b   = (const float*)d_in[12];
    const float* Wr     = (const float*)d_in[13];
    const float* br     = (const float*)d_in[14];
    const float* W_up   = (const float*)d_in[15];
    const float* b_up   = (const float*)d_in[16];
    const float* W_new  = (const float*)d_in[17];
    const float* b_new  = (const float*)d_in[18];
    const float* W_down = (const float*)d_in[19];
    const float* b_down = (const float*)d_in[20];

    float* out = (float*)d_out;
    float* ws  = (float*)d_ws;

    bf16* WupT   = (bf16*)(ws + OFF_WUP_T);
    bf16* WnewT  = (bf16*)(ws + OFF_WNEW_T);
    bf16* WdownT = (bf16*)(ws + OFF_WDOWN_T);
    float* q     = ws + OFF_QKV;
    float* k     = ws + OFF_QKV + TH;
    float* v     = ws + OFF_QKV + 2 * TH;
    float* tmp   = ws + OFF_QKV + 3 * TH;
    bf16* act    = (bf16*)(ws + OFF_QKV);   // aliases q/k/v/tmp (dead by then)
    float* ctx   = ws + OFF_CTX;
    bf16* xlb    = (bf16*)(ws + OFF_XLB);
    float* wgt   = ws + OFF_WGT;
    int* counts  = (int*)(ws + OFF_COUNTS);
    int* lists   = (int*)(ws + OFF_LISTS);

    init_counts_kernel<<<1, 64, 0, stream>>>(counts);

    // expert weight transpose+convert
    transpose_bf16_kernel<<<dim3(48, 12, cE), 256, 0, stream>>>(W_up, WupT, cH, cI);
    transpose_bf16_kernel<<<dim3(48, 12, cE), 256, 0, stream>>>(W_new, WnewT, cH, cI);
    transpose_bf16_kernel<<<dim3(12, 48, cE), 256, 0, stream>>>(W_down, WdownT, cI, cH);

    // fp32 pre-router path (selection-exact)
    gemm_qkv_kernel<<<dim3(cH / 128, cT / 128, 3), 256, 0, stream>>>(
        x, Wq, Wk, Wv, bq, bk, bv, q, k, v);
    attn_kernel<<<dim3(cS / 64, cNH, cB), 256, 0, stream>>>(q, k, v, ctx);
    gemm_bias_kernel<<<dim3(cH / 128, cT / 128), 256, 0, stream>>>(ctx, Wo, bo, tmp, cT, cH, cH);
    ln_router_kernel<<<cT, 256, 0, stream>>>(
        tmp, x, ln1g, ln1b, ln2g, ln2b, Wr, br,
        out, xlb, out + TH, wgt, counts, lists);

    // bf16 MFMA experts (scatter-add into out)
    expert_up_mfma_kernel<<<dim3(cI / 64, cT / 128, cE), 256, 0, stream>>>(
        xlb, WupT, WnewT, b_up, b_new, counts, lists, act);
    expert_down_mfma_kernel<<<dim3(cH / 128, cT / 128, cE), 256, 0, stream>>>(
        act, WdownT, b_down, counts, lists, wgt, out);
}